// Round 1
// baseline (905.025 us; speedup 1.0000x reference)
//
#include <hip/hip_runtime.h>
#include <hip/hip_bf16.h>
#include <cstdint>
#include <cstddef>

typedef __hip_bfloat16 bf16;
typedef __bf16 bf16x8 __attribute__((ext_vector_type(8)));
typedef float f32x4 __attribute__((ext_vector_type(4)));

#define DEVFN static __device__ __forceinline__

// async global->LDS, 16B per lane. LDS dest must be wave-uniform base + lane*16.
DEVFN void async16(const void* g, void* l) {
  __builtin_amdgcn_global_load_lds(
      (const __attribute__((address_space(1))) uint32_t*)g,
      (__attribute__((address_space(3))) uint32_t*)l, 16, 0, 0);
}

DEVFN float eluf(float v) { return v > 0.f ? v : expm1f(v); }
DEVFN float softplusf(float x) {
  return x > 0.f ? x + log1pf(expf(-x)) : log1pf(expf(x));
}

// ---------------------------------------------------------------------------
// float -> bf16 convert (x), 4 elems/thread
__global__ __launch_bounds__(256) void cvt_x_k(const float* __restrict__ src,
                                               bf16* __restrict__ dst) {
  size_t i = ((size_t)blockIdx.x * 256 + threadIdx.x) * 4;
  float4 v = *(const float4*)(src + i);
  union { bf16 h[4]; uint2 u; } o;
  o.h[0] = __float2bfloat16(v.x);
  o.h[1] = __float2bfloat16(v.y);
  o.h[2] = __float2bfloat16(v.z);
  o.h[3] = __float2bfloat16(v.w);
  *(uint2*)(dst + i) = o.u;
}

// transpose + convert: src fp32 [R][C] -> dst bf16 [C][R]; batch on blockIdx.z
__global__ __launch_bounds__(256) void trcvt_k(const float* __restrict__ src,
                                               bf16* __restrict__ dst, int R, int C) {
  __shared__ float tile[32][33];
  src += (size_t)blockIdx.z * R * C;
  dst += (size_t)blockIdx.z * R * C;
  const int c0 = blockIdx.x * 32, r0 = blockIdx.y * 32;
  const int tx = threadIdx.x & 31, ty = threadIdx.x >> 5;
#pragma unroll
  for (int rr = ty; rr < 32; rr += 8)
    tile[rr][tx] = src[(size_t)(r0 + rr) * C + c0 + tx];
  __syncthreads();
#pragma unroll
  for (int rr = ty; rr < 32; rr += 8)
    dst[(size_t)(c0 + rr) * R + r0 + tx] = __float2bfloat16(tile[tx][rr]);
}

// partition rows by treatment t (order within bucket irrelevant)
__global__ __launch_bounds__(256) void bucketize_k(const int* __restrict__ t,
                                                   int* __restrict__ cnt,
                                                   int* __restrict__ lists) {
  int b = blockIdx.x * 256 + threadIdx.x;
  int tt = t[b];
  int pos = atomicAdd(&cnt[tt], 1);
  lists[tt * 16384 + pos] = b;
}

// ---------------------------------------------------------------------------
// bf16 MFMA GEMM, m97 structure: 128x128 tile, BK=32, 4 waves (2x2), each wave
// 64x64 via 4x4 frags of 16x16x32. A [M][K] row-major bf16, Bt [N][K] bf16.
// Epilogue: +bias, (optional rank-2 z-fix), ELU, store bf16 to C [M][N].
template <int ZEXTRA>
__global__ __launch_bounds__(256) void gemm_k(
    const bf16* __restrict__ A, const bf16* __restrict__ Bt,
    bf16* __restrict__ C, const float* __restrict__ bias, int N, int K,
    const float* __restrict__ yv, const float* __restrict__ dv,
    const float* __restrict__ zr0, const float* __restrict__ zr1) {
  __shared__ bf16 As[128 * 32];
  __shared__ bf16 Bs[128 * 32];
  const int tid = threadIdx.x;
  const int lane = tid & 63;
  const int wid = tid >> 6;
  const int wm = wid >> 1, wn = wid & 1;
  const int quad = lane >> 4, l15 = lane & 15;
  const int bm0 = blockIdx.y * 128;
  const int bn0 = blockIdx.x * 128;

  const int sr = tid >> 2;          // staging row within 64-row half-tile
  const int sc = (tid & 3) * 8;     // staging k-offset (elements)
  const bf16* gA0 = A + (size_t)(bm0 + sr) * K + sc;
  const bf16* gA1 = gA0 + (size_t)64 * K;
  const bf16* gB0 = Bt + (size_t)(bn0 + sr) * K + sc;
  const bf16* gB1 = gB0 + (size_t)64 * K;
  bf16* lA0 = &As[(size_t)tid * 8];
  bf16* lA1 = &As[2048 + (size_t)tid * 8];
  bf16* lB0 = &Bs[(size_t)tid * 8];
  bf16* lB1 = &Bs[2048 + (size_t)tid * 8];

  const bf16* aBase = &As[(wm * 64 + l15) * 32 + quad * 8];
  const bf16* bBase = &Bs[(wn * 64 + l15) * 32 + quad * 8];

  f32x4 acc[4][4] = {};
  const int kiters = K >> 5;
  for (int kt = 0; kt < kiters; ++kt) {
    async16(gA0, lA0); async16(gA1, lA1);
    async16(gB0, lB0); async16(gB1, lB1);
    gA0 += 32; gA1 += 32; gB0 += 32; gB1 += 32;
    __syncthreads();
    bf16x8 af[4], bfv[4];
#pragma unroll
    for (int r = 0; r < 4; ++r) af[r] = *(const bf16x8*)(aBase + r * 512);
#pragma unroll
    for (int c = 0; c < 4; ++c) bfv[c] = *(const bf16x8*)(bBase + c * 512);
#pragma unroll
    for (int r = 0; r < 4; ++r)
#pragma unroll
      for (int c = 0; c < 4; ++c)
        acc[r][c] = __builtin_amdgcn_mfma_f32_16x16x32_bf16(af[r], bfv[c], acc[r][c], 0, 0, 0);
    __syncthreads();
  }

  float bv[4], z0[4], z1[4];
#pragma unroll
  for (int c = 0; c < 4; ++c) {
    int gn = bn0 + wn * 64 + c * 16 + l15;
    bv[c] = bias[gn];
    if (ZEXTRA) { z0[c] = zr0[gn]; z1[c] = zr1[gn]; }
  }
#pragma unroll
  for (int r = 0; r < 4; ++r) {
#pragma unroll
    for (int q = 0; q < 4; ++q) {
      int gm = bm0 + wm * 64 + r * 16 + quad * 4 + q;
      float yy = 0.f, dd2 = 0.f;
      if (ZEXTRA) { yy = yv[gm]; dd2 = dv[gm]; }
#pragma unroll
      for (int c = 0; c < 4; ++c) {
        int gn = bn0 + wn * 64 + c * 16 + l15;
        float v = acc[r][c][q] + bv[c];
        if (ZEXTRA) v += yy * z0[c] + dd2 * z1[c];
        C[(size_t)gm * N + gn] = __float2bfloat16(eluf(v));
      }
    }
  }
}

// ---------------------------------------------------------------------------
// z-head: bucketed/grouped GEMM. A rows gathered via per-bucket index list,
// B = zhWt[k] bf16 [512][1024]. Epilogue writes head-transformed fp32 straight
// into out[:, 11:523]. grid = (4 n-tiles, 128 m-tiles(max), 7 buckets).
__global__ __launch_bounds__(256) void zhead_k(
    const bf16* __restrict__ hz, const bf16* __restrict__ zhWt,
    const float* __restrict__ zhb, const int* __restrict__ lists,
    const int* __restrict__ cnts, float* __restrict__ out) {
  const int kb = blockIdx.z;
  const int cnt = cnts[kb];
  const int bm0 = blockIdx.y * 128;
  if (bm0 >= cnt) return;
  __shared__ bf16 As[128 * 32];
  __shared__ bf16 Bs[128 * 32];
  const int tid = threadIdx.x;
  const int lane = tid & 63;
  const int wid = tid >> 6;
  const int wm = wid >> 1, wn = wid & 1;
  const int quad = lane >> 4, l15 = lane & 15;
  const int bn0 = blockIdx.x * 128;
  const int* list = lists + kb * 16384;

  const int sr = tid >> 2;
  const int sc = (tid & 3) * 8;
  int lr0 = bm0 + sr;       if (lr0 >= cnt) lr0 = cnt - 1;
  int lr1 = bm0 + 64 + sr;  if (lr1 >= cnt) lr1 = cnt - 1;
  const int gr0 = list[lr0], gr1 = list[lr1];
  const bf16* gA0 = hz + (size_t)gr0 * 1024 + sc;
  const bf16* gA1 = hz + (size_t)gr1 * 1024 + sc;
  const bf16* gB0 = zhWt + (size_t)kb * 512 * 1024 + (size_t)(bn0 + sr) * 1024 + sc;
  const bf16* gB1 = gB0 + (size_t)64 * 1024;
  bf16* lA0 = &As[(size_t)tid * 8];
  bf16* lA1 = &As[2048 + (size_t)tid * 8];
  bf16* lB0 = &Bs[(size_t)tid * 8];
  bf16* lB1 = &Bs[2048 + (size_t)tid * 8];

  const bf16* aBase = &As[(wm * 64 + l15) * 32 + quad * 8];
  const bf16* bBase = &Bs[(wn * 64 + l15) * 32 + quad * 8];

  f32x4 acc[4][4] = {};
  for (int kt = 0; kt < 32; ++kt) {
    async16(gA0, lA0); async16(gA1, lA1);
    async16(gB0, lB0); async16(gB1, lB1);
    gA0 += 32; gA1 += 32; gB0 += 32; gB1 += 32;
    __syncthreads();
    bf16x8 af[4], bfv[4];
#pragma unroll
    for (int r = 0; r < 4; ++r) af[r] = *(const bf16x8*)(aBase + r * 512);
#pragma unroll
    for (int c = 0; c < 4; ++c) bfv[c] = *(const bf16x8*)(bBase + c * 512);
#pragma unroll
    for (int r = 0; r < 4; ++r)
#pragma unroll
      for (int c = 0; c < 4; ++c)
        acc[r][c] = __builtin_amdgcn_mfma_f32_16x16x32_bf16(af[r], bfv[c], acc[r][c], 0, 0, 0);
    __syncthreads();
  }

  const float* bias = zhb + (size_t)kb * 512;
  float bv[4]; int gnn[4];
#pragma unroll
  for (int c = 0; c < 4; ++c) {
    gnn[c] = bn0 + wn * 64 + c * 16 + l15;
    bv[c] = bias[gnn[c]];
  }
#pragma unroll
  for (int r = 0; r < 4; ++r) {
#pragma unroll
    for (int q = 0; q < 4; ++q) {
      int lm = bm0 + wm * 64 + r * 16 + quad * 4 + q;
      if (lm < cnt) {
        int gm = list[lm];
        size_t ob = (size_t)gm * 523 + 11;  // cols 11..266 loc, 267..522 scale
#pragma unroll
        for (int c = 0; c < 4; ++c) {
          float v = acc[r][c][q] + bv[c];
          int n = gnn[c];
          out[ob + n] = (n < 256) ? fminf(fmaxf(v, -100.f), 100.f)
                                  : fminf(softplusf(v) + 0.001f, 100.f);
        }
      }
    }
  }
}

// ---------------------------------------------------------------------------
// y/d heads: one wave per row, dot(h[1024], head[t][:,0:2]) -> Normal head.
__global__ __launch_bounds__(256) void yd_head_k(
    const bf16* __restrict__ hy, const bf16* __restrict__ hd,
    const int* __restrict__ t, const float* __restrict__ yhW,
    const float* __restrict__ yhb, const float* __restrict__ dhW,
    const float* __restrict__ dhb, float* __restrict__ out) {
  const int wv = threadIdx.x >> 6, lane = threadIdx.x & 63;
  const int b = blockIdx.x * 4 + wv;
  const int tb = t[b];
  const float* yW = yhW + (size_t)tb * 2048;
  const float* dW = dhW + (size_t)tb * 2048;
  float s0 = 0.f, s1 = 0.f, s2 = 0.f, s3 = 0.f;
  for (int i = lane; i < 1024; i += 64) {
    float a = __bfloat162float(hy[(size_t)b * 1024 + i]);
    float c = __bfloat162float(hd[(size_t)b * 1024 + i]);
    s0 += a * yW[2 * i];  s1 += a * yW[2 * i + 1];
    s2 += c * dW[2 * i];  s3 += c * dW[2 * i + 1];
  }
#pragma unroll
  for (int off = 32; off > 0; off >>= 1) {
    s0 += __shfl_down(s0, off);
    s1 += __shfl_down(s1, off);
    s2 += __shfl_down(s2, off);
    s3 += __shfl_down(s3, off);
  }
  if (lane == 0) {
    float yl = fminf(fmaxf(s0 + yhb[tb * 2], -1e6f), 1e6f);
    float ys = fminf(softplusf(s1 + yhb[tb * 2 + 1]) + 1e-3f, 1e6f);
    float dl = fminf(fmaxf(s2 + dhb[tb * 2], -1e6f), 1e6f);
    float dsc = fminf(softplusf(s3 + dhb[tb * 2 + 1]) + 1e-3f, 1e6f);
    size_t o = (size_t)b * 523;
    out[o + 7] = yl; out[o + 8] = ys; out[o + 9] = dl; out[o + 10] = dsc;
  }
}

// t logits: one wave per row, ht2[256] @ tw2[256][7] + tb2, elu, clip.
__global__ __launch_bounds__(256) void tlogits_k(
    const bf16* __restrict__ ht2, const float* __restrict__ tw2,
    const float* __restrict__ tb2, float* __restrict__ out) {
  const int wv = threadIdx.x >> 6, lane = threadIdx.x & 63;
  const int b = blockIdx.x * 4 + wv;
  float h[4];
#pragma unroll
  for (int j = 0; j < 4; ++j)
    h[j] = __bfloat162float(ht2[(size_t)b * 256 + lane * 4 + j]);
  float pp[7];
#pragma unroll
  for (int kk = 0; kk < 7; ++kk) {
    float s = 0.f;
#pragma unroll
    for (int j = 0; j < 4; ++j) s += h[j] * tw2[(lane * 4 + j) * 7 + kk];
    pp[kk] = s;
  }
#pragma unroll
  for (int kk = 0; kk < 7; ++kk)
#pragma unroll
    for (int off = 32; off > 0; off >>= 1) pp[kk] += __shfl_down(pp[kk], off);
  if (lane == 0) {
#pragma unroll
    for (int kk = 0; kk < 7; ++kk) {
      float v = eluf(pp[kk] + tb2[kk]);
      out[(size_t)b * 523 + kk] = fminf(fmaxf(v, -10.f), 10.f);
    }
  }
}

// ---------------------------------------------------------------------------
extern "C" void kernel_launch(void* const* d_in, const int* in_sizes, int n_in,
                              void* d_out, int out_size, void* d_ws, size_t ws_size,
                              hipStream_t stream) {
  const float* x   = (const float*)d_in[0];
  const int*   t   = (const int*)d_in[1];
  const float* yv  = (const float*)d_in[2];
  const float* dv  = (const float*)d_in[3];
  const float* tw0 = (const float*)d_in[4];
  const float* tb0 = (const float*)d_in[5];
  const float* tw1 = (const float*)d_in[6];
  const float* tb1 = (const float*)d_in[7];
  const float* tw2 = (const float*)d_in[8];
  const float* tb2 = (const float*)d_in[9];
  const float* yw0 = (const float*)d_in[10];
  const float* yb0 = (const float*)d_in[11];
  const float* yw1 = (const float*)d_in[12];
  const float* yb1 = (const float*)d_in[13];
  const float* yhW = (const float*)d_in[14];
  const float* yhb = (const float*)d_in[15];
  const float* dw0 = (const float*)d_in[16];
  const float* db0 = (const float*)d_in[17];
  const float* dw1 = (const float*)d_in[18];
  const float* db1 = (const float*)d_in[19];
  const float* dhW = (const float*)d_in[20];
  const float* dhb = (const float*)d_in[21];
  const float* zw0 = (const float*)d_in[22];
  const float* zb0 = (const float*)d_in[23];
  const float* zw1 = (const float*)d_in[24];
  const float* zb1 = (const float*)d_in[25];
  const float* zhW = (const float*)d_in[26];
  const float* zhb = (const float*)d_in[27];
  float* out = (float*)d_out;

  const int B = 16384;
  char* p = (char*)d_ws;
  auto take = [&](size_t bytes) {
    char* r = p;
    p += (bytes + 255) & ~(size_t)255;
    return r;
  };
  bf16* yw0t  = (bf16*)take((size_t)1024 * 1024 * 2);
  bf16* dw0t  = (bf16*)take((size_t)1024 * 1024 * 2);
  bf16* zw0xt = (bf16*)take((size_t)1024 * 1024 * 2);
  bf16* tw0t  = (bf16*)take((size_t)256 * 1024 * 2);
  bf16* yw1t  = (bf16*)take((size_t)1024 * 1024 * 2);
  bf16* dw1t  = (bf16*)take((size_t)1024 * 1024 * 2);
  bf16* zw1t  = (bf16*)take((size_t)1024 * 1024 * 2);
  bf16* tw1t  = (bf16*)take((size_t)256 * 256 * 2);
  bf16* zhWt  = (bf16*)take((size_t)7 * 512 * 1024 * 2);
  bf16* xb    = (bf16*)take((size_t)B * 1024 * 2);
  bf16* a1    = (bf16*)take((size_t)B * 1024 * 2);
  bf16* hy    = (bf16*)take((size_t)B * 1024 * 2);
  bf16* hd    = (bf16*)take((size_t)B * 1024 * 2);
  bf16* ht2   = (bf16*)take((size_t)B * 256 * 2);
  int*  cnt   = (int*)take(8 * sizeof(int));
  int*  lists = (int*)take((size_t)7 * B * sizeof(int));
  bf16* hz    = xb;  // xb dead after the last first-layer GEMM (z path runs last)

  // --- prep: buckets, bf16 conversions, weight transposes
  hipMemsetAsync(cnt, 0, 8 * sizeof(int), stream);
  bucketize_k<<<B / 256, 256, 0, stream>>>(t, cnt, lists);
  cvt_x_k<<<(B * 1024) / (256 * 4), 256, 0, stream>>>(x, xb);
  trcvt_k<<<dim3(32, 32, 1), 256, 0, stream>>>(yw0, yw0t, 1024, 1024);
  trcvt_k<<<dim3(32, 32, 1), 256, 0, stream>>>(dw0, dw0t, 1024, 1024);
  trcvt_k<<<dim3(32, 32, 1), 256, 0, stream>>>(zw0 + 2 * 1024, zw0xt, 1024, 1024);
  trcvt_k<<<dim3(8, 32, 1), 256, 0, stream>>>(tw0, tw0t, 1024, 256);
  trcvt_k<<<dim3(32, 32, 1), 256, 0, stream>>>(yw1, yw1t, 1024, 1024);
  trcvt_k<<<dim3(32, 32, 1), 256, 0, stream>>>(dw1, dw1t, 1024, 1024);
  trcvt_k<<<dim3(32, 32, 1), 256, 0, stream>>>(zw1, zw1t, 1024, 1024);
  trcvt_k<<<dim3(8, 8, 1), 256, 0, stream>>>(tw1, tw1t, 256, 256);
  trcvt_k<<<dim3(16, 32, 7), 256, 0, stream>>>(zhW, zhWt, 1024, 512);

  // --- y path
  gemm_k<0><<<dim3(8, 128), 256, 0, stream>>>(xb, yw0t, a1, yb0, 1024, 1024,
                                              nullptr, nullptr, nullptr, nullptr);
  gemm_k<0><<<dim3(8, 128), 256, 0, stream>>>(a1, yw1t, hy, yb1, 1024, 1024,
                                              nullptr, nullptr, nullptr, nullptr);
  // --- d path
  gemm_k<0><<<dim3(8, 128), 256, 0, stream>>>(xb, dw0t, a1, db0, 1024, 1024,
                                              nullptr, nullptr, nullptr, nullptr);
  gemm_k<0><<<dim3(8, 128), 256, 0, stream>>>(a1, dw1t, hd, db1, 1024, 1024,
                                              nullptr, nullptr, nullptr, nullptr);
  // --- t path
  gemm_k<0><<<dim3(2, 128), 256, 0, stream>>>(xb, tw0t, a1, tb0, 256, 1024,
                                              nullptr, nullptr, nullptr, nullptr);
  gemm_k<0><<<dim3(2, 128), 256, 0, stream>>>(a1, tw1t, ht2, tb1, 256, 256,
                                              nullptr, nullptr, nullptr, nullptr);
  // --- z path (last: frees xb for hz); cat([y,d,x])@zw0 = x@zw0[2:] + y*r0 + d*r1
  gemm_k<1><<<dim3(8, 128), 256, 0, stream>>>(xb, zw0xt, a1, zb0, 1024, 1024,
                                              yv, dv, zw0, zw0 + 1024);
  gemm_k<0><<<dim3(8, 128), 256, 0, stream>>>(a1, zw1t, hz, zb1, 1024, 1024,
                                              nullptr, nullptr, nullptr, nullptr);
  // --- heads
  zhead_k<<<dim3(4, 128, 7), 256, 0, stream>>>(hz, zhWt, zhb, lists, cnt, out);
  yd_head_k<<<B / 4, 256, 0, stream>>>(hy, hd, t, yhW, yhb, dhW, dhb, out);
  tlogits_k<<<B / 4, 256, 0, stream>>>(ht2, tw2, tb2, out);
}

// Round 2
// 777.201 us; speedup vs baseline: 1.1645x; 1.1645x over previous
//
#include <hip/hip_runtime.h>
#include <hip/hip_bf16.h>
#include <cstdint>
#include <cstddef>

typedef __hip_bfloat16 bf16;
typedef __bf16 bf16x8 __attribute__((ext_vector_type(8)));
typedef float f32x4 __attribute__((ext_vector_type(4)));

#define DEVFN static __device__ __forceinline__

// async global->LDS, 16B per lane. LDS dest must be wave-uniform base + lane*16.
DEVFN void async16(const void* g, void* l) {
  __builtin_amdgcn_global_load_lds(
      (const __attribute__((address_space(1))) uint32_t*)g,
      (__attribute__((address_space(3))) uint32_t*)l, 16, 0, 0);
}

DEVFN float eluf(float v) { return v > 0.f ? v : expm1f(v); }
DEVFN float softplusf(float x) {
  return x > 0.f ? x + log1pf(expf(-x)) : log1pf(expf(x));
}

// ---------------------------------------------------------------------------
// shared 128x128-tile K-loop (BK=32, 4 waves 2x2, 4x4 frags of 16x16x32 bf16)
template <int KITERS>
DEVFN void kloop128(const bf16* gA0, const bf16* gA1, const bf16* gB0,
                    const bf16* gB1, bf16* lA0, bf16* lA1, bf16* lB0, bf16* lB1,
                    const bf16* aBase, const bf16* bBase, f32x4 (&acc)[4][4]) {
  for (int kt = 0; kt < KITERS; ++kt) {
    async16(gA0, lA0); async16(gA1, lA1);
    async16(gB0, lB0); async16(gB1, lB1);
    gA0 += 32; gA1 += 32; gB0 += 32; gB1 += 32;
    __syncthreads();
    bf16x8 af[4], bfv[4];
#pragma unroll
    for (int r = 0; r < 4; ++r) af[r] = *(const bf16x8*)(aBase + r * 512);
#pragma unroll
    for (int c = 0; c < 4; ++c) bfv[c] = *(const bf16x8*)(bBase + c * 512);
#pragma unroll
    for (int r = 0; r < 4; ++r)
#pragma unroll
      for (int c = 0; c < 4; ++c)
        acc[r][c] = __builtin_amdgcn_mfma_f32_16x16x32_bf16(af[r], bfv[c], acc[r][c], 0, 0, 0);
    __syncthreads();
  }
}

// ---------------------------------------------------------------------------
// prep kernels
__global__ __launch_bounds__(256) void cvt_x_k(const float* __restrict__ src,
                                               bf16* __restrict__ dst) {
  size_t i = ((size_t)blockIdx.x * 256 + threadIdx.x) * 8;
  float4 v0 = *(const float4*)(src + i);
  float4 v1 = *(const float4*)(src + i + 4);
  union { bf16 h[8]; uint4 u; } o;
  o.h[0] = __float2bfloat16(v0.x); o.h[1] = __float2bfloat16(v0.y);
  o.h[2] = __float2bfloat16(v0.z); o.h[3] = __float2bfloat16(v0.w);
  o.h[4] = __float2bfloat16(v1.x); o.h[5] = __float2bfloat16(v1.y);
  o.h[6] = __float2bfloat16(v1.z); o.h[7] = __float2bfloat16(v1.w);
  *(uint4*)(dst + i) = o.u;
}

DEVFN void transpose_tile(const float* src, bf16* dst, int R, int C) {
  __shared__ float tile[32][33];
  const int c0 = blockIdx.x * 32, r0 = blockIdx.y * 32;
  const int tx = threadIdx.x & 31, ty = threadIdx.x >> 5;
#pragma unroll
  for (int rr = ty; rr < 32; rr += 8)
    tile[rr][tx] = src[(size_t)(r0 + rr) * C + c0 + tx];
  __syncthreads();
#pragma unroll
  for (int rr = ty; rr < 32; rr += 8)
    dst[(size_t)(c0 + rr) * R + r0 + tx] = __float2bfloat16(tile[tx][rr]);
}

// generic transpose+cvt src[R][C] -> dst[C][R], batched on z (same src each z-step)
__global__ __launch_bounds__(256) void trcvt_k(const float* __restrict__ src,
                                               bf16* __restrict__ dst, int R, int C) {
  transpose_tile(src + (size_t)blockIdx.z * R * C,
                 dst + (size_t)blockIdx.z * R * C, R, C);
}

// 4-source transpose into concatenated BtL1 [3328][1024]
__global__ __launch_bounds__(256) void trcvt4_k(
    const float* __restrict__ s0, const float* __restrict__ s1,
    const float* __restrict__ s2, const float* __restrict__ s3,
    bf16* __restrict__ dst) {
  const int z = blockIdx.z;
  const float* src = (z == 0) ? s0 : (z == 1) ? s1 : (z == 2) ? s2 : s3;
  const int C = (z == 3) ? 256 : 1024;
  if ((int)blockIdx.x * 32 >= C) return;
  transpose_tile(src, dst + (size_t)z * 1024 * 1024, 1024, C);
}

// 3-source transpose into concatenated BtL2 [3072][1024]
__global__ __launch_bounds__(256) void trcvt3_k(
    const float* __restrict__ s0, const float* __restrict__ s1,
    const float* __restrict__ s2, bf16* __restrict__ dst) {
  const int z = blockIdx.z;
  const float* src = (z == 0) ? s0 : (z == 1) ? s1 : s2;
  transpose_tile(src, dst + (size_t)z * 1024 * 1024, 1024, 1024);
}

// bias / rank-2 vector concatenation (3328 threads)
__global__ __launch_bounds__(256) void biascat_k(
    const float* __restrict__ yb0, const float* __restrict__ db0,
    const float* __restrict__ zb0, const float* __restrict__ tb0,
    const float* __restrict__ zw0, const float* __restrict__ yb1,
    const float* __restrict__ db1, const float* __restrict__ zb1,
    float* __restrict__ biasAll, float* __restrict__ r0All,
    float* __restrict__ r1All, float* __restrict__ biasL2) {
  int i = blockIdx.x * 256 + threadIdx.x;
  if (i >= 3328) return;
  float b;
  if (i < 1024) b = yb0[i];
  else if (i < 2048) b = db0[i - 1024];
  else if (i < 3072) b = zb0[i - 2048];
  else b = tb0[i - 3072];
  biasAll[i] = b;
  bool inz = (i >= 2048 && i < 3072);
  r0All[i] = inz ? zw0[i - 2048] : 0.f;
  r1All[i] = inz ? zw0[1024 + (i - 2048)] : 0.f;
  if (i < 3072)
    biasL2[i] = (i < 1024) ? yb1[i] : (i < 2048) ? db1[i - 1024] : zb1[i - 2048];
}

// bucket bookkeeping
__global__ __launch_bounds__(256) void bucketize_k(const int* __restrict__ t,
                                                   int* __restrict__ cnt,
                                                   int* __restrict__ pos) {
  int b = blockIdx.x * 256 + threadIdx.x;
  pos[b] = atomicAdd(&cnt[t[b]], 1);
}
__global__ void segk(const int* __restrict__ cnt, int* __restrict__ seg) {
  if (threadIdx.x == 0) {
    int s = 0;
    for (int k = 0; k < 7; ++k) { seg[k] = s; s += cnt[k]; }
    seg[7] = s;
  }
}
__global__ __launch_bounds__(256) void rankk(const int* __restrict__ t,
                                             const int* __restrict__ pos,
                                             const int* __restrict__ seg,
                                             int* __restrict__ rank,
                                             int* __restrict__ sids) {
  int b = blockIdx.x * 256 + threadIdx.x;
  int r = seg[t[b]] + pos[b];
  rank[b] = r;
  sids[r] = b;
}

// ---------------------------------------------------------------------------
// fused layer-1: [16384,1024] x [1024,3328] -> {a1y,a1d,a1z,ht1}, ELU + rank-2 z fix
__global__ __launch_bounds__(256) void gemm_l1_k(
    const bf16* __restrict__ A, const bf16* __restrict__ Bt,
    const float* __restrict__ biasAll, const float* __restrict__ r0All,
    const float* __restrict__ r1All, const float* __restrict__ yv,
    const float* __restrict__ dv, bf16* __restrict__ a1y,
    bf16* __restrict__ a1d, bf16* __restrict__ a1z, bf16* __restrict__ ht1) {
  __shared__ bf16 As[128 * 32];
  __shared__ bf16 Bs[128 * 32];
  const int tid = threadIdx.x, lane = tid & 63, wid = tid >> 6;
  const int wm = wid >> 1, wn = wid & 1, quad = lane >> 4, l15 = lane & 15;
  const int bm0 = blockIdx.y * 128, bn0 = blockIdx.x * 128;
  const int sr = tid >> 2, sc = (tid & 3) * 8;
  f32x4 acc[4][4] = {};
  kloop128<32>(A + (size_t)(bm0 + sr) * 1024 + sc,
               A + (size_t)(bm0 + 64 + sr) * 1024 + sc,
               Bt + (size_t)(bn0 + sr) * 1024 + sc,
               Bt + (size_t)(bn0 + 64 + sr) * 1024 + sc,
               &As[tid * 8], &As[2048 + tid * 8], &Bs[tid * 8], &Bs[2048 + tid * 8],
               &As[(wm * 64 + l15) * 32 + quad * 8],
               &Bs[(wn * 64 + l15) * 32 + quad * 8], acc);
  const int g = bn0 >> 10;
  bf16* dst = (g == 0) ? a1y : (g == 1) ? a1d : (g == 2) ? a1z : ht1;
  const int ldc = (g == 3) ? 256 : 1024;
  const int colb = bn0 - g * 1024;
  float bv[4], z0[4], z1[4];
#pragma unroll
  for (int c = 0; c < 4; ++c) {
    int gn = bn0 + wn * 64 + c * 16 + l15;
    bv[c] = biasAll[gn]; z0[c] = r0All[gn]; z1[c] = r1All[gn];
  }
#pragma unroll
  for (int r = 0; r < 4; ++r) {
#pragma unroll
    for (int q = 0; q < 4; ++q) {
      int gm = bm0 + wm * 64 + r * 16 + quad * 4 + q;
      float yy = yv[gm], dd = dv[gm];
#pragma unroll
      for (int c = 0; c < 4; ++c) {
        float v = acc[r][c][q] + bv[c] + yy * z0[c] + dd * z1[c];
        dst[(size_t)gm * ldc + colb + wn * 64 + c * 16 + l15] = __float2bfloat16(eluf(v));
      }
    }
  }
}

// fused layer-2: per-n-group A in {a1y,a1d,a1z}; out hyd[B][2048] / hzg permuted
__global__ __launch_bounds__(256) void gemm_l2_k(
    const bf16* __restrict__ a1y, const bf16* __restrict__ a1d,
    const bf16* __restrict__ a1z, const bf16* __restrict__ Bt,
    const float* __restrict__ biasL2, bf16* __restrict__ hyd,
    bf16* __restrict__ hzg, const int* __restrict__ rank) {
  __shared__ bf16 As[128 * 32];
  __shared__ bf16 Bs[128 * 32];
  const int tid = threadIdx.x, lane = tid & 63, wid = tid >> 6;
  const int wm = wid >> 1, wn = wid & 1, quad = lane >> 4, l15 = lane & 15;
  const int bm0 = blockIdx.y * 128, bn0 = blockIdx.x * 128;
  const int g = bn0 >> 10;
  const bf16* A = (g == 0) ? a1y : (g == 1) ? a1d : a1z;
  const int sr = tid >> 2, sc = (tid & 3) * 8;
  f32x4 acc[4][4] = {};
  kloop128<32>(A + (size_t)(bm0 + sr) * 1024 + sc,
               A + (size_t)(bm0 + 64 + sr) * 1024 + sc,
               Bt + (size_t)(bn0 + sr) * 1024 + sc,
               Bt + (size_t)(bn0 + 64 + sr) * 1024 + sc,
               &As[tid * 8], &As[2048 + tid * 8], &Bs[tid * 8], &Bs[2048 + tid * 8],
               &As[(wm * 64 + l15) * 32 + quad * 8],
               &Bs[(wn * 64 + l15) * 32 + quad * 8], acc);
  float bv[4];
#pragma unroll
  for (int c = 0; c < 4; ++c) bv[c] = biasL2[bn0 + wn * 64 + c * 16 + l15];
#pragma unroll
  for (int r = 0; r < 4; ++r) {
#pragma unroll
    for (int q = 0; q < 4; ++q) {
      int gm = bm0 + wm * 64 + r * 16 + quad * 4 + q;
      size_t rowoff = (g == 2) ? (size_t)rank[gm] * 1024 + (size_t)(bn0 - 2048)
                               : (size_t)gm * 2048 + (size_t)bn0;
      bf16* dst = (g == 2) ? hzg : hyd;
#pragma unroll
      for (int c = 0; c < 4; ++c) {
        float v = acc[r][c][q] + bv[c];
        dst[rowoff + wn * 64 + c * 16 + l15] = __float2bfloat16(eluf(v));
      }
    }
  }
}

// t layer-2: [16384,256] x [256,256], ELU
__global__ __launch_bounds__(256) void gemm_t1_k(const bf16* __restrict__ A,
                                                 const bf16* __restrict__ Bt,
                                                 const float* __restrict__ bias,
                                                 bf16* __restrict__ C) {
  __shared__ bf16 As[128 * 32];
  __shared__ bf16 Bs[128 * 32];
  const int tid = threadIdx.x, lane = tid & 63, wid = tid >> 6;
  const int wm = wid >> 1, wn = wid & 1, quad = lane >> 4, l15 = lane & 15;
  const int bm0 = blockIdx.y * 128, bn0 = blockIdx.x * 128;
  const int sr = tid >> 2, sc = (tid & 3) * 8;
  f32x4 acc[4][4] = {};
  kloop128<8>(A + (size_t)(bm0 + sr) * 256 + sc,
              A + (size_t)(bm0 + 64 + sr) * 256 + sc,
              Bt + (size_t)(bn0 + sr) * 256 + sc,
              Bt + (size_t)(bn0 + 64 + sr) * 256 + sc,
              &As[tid * 8], &As[2048 + tid * 8], &Bs[tid * 8], &Bs[2048 + tid * 8],
              &As[(wm * 64 + l15) * 32 + quad * 8],
              &Bs[(wn * 64 + l15) * 32 + quad * 8], acc);
  float bv[4];
#pragma unroll
  for (int c = 0; c < 4; ++c) bv[c] = bias[bn0 + wn * 64 + c * 16 + l15];
#pragma unroll
  for (int r = 0; r < 4; ++r)
#pragma unroll
    for (int q = 0; q < 4; ++q) {
      int gm = bm0 + wm * 64 + r * 16 + quad * 4 + q;
#pragma unroll
      for (int c = 0; c < 4; ++c)
        C[(size_t)gm * 256 + bn0 + wn * 64 + c * 16 + l15] =
            __float2bfloat16(eluf(acc[r][c][q] + bv[c]));
    }
}

// ---------------------------------------------------------------------------
// z-head: per-bucket GEMM on permuted contiguous rows, 128x64 tiles.
__global__ __launch_bounds__(256) void zhead_k(
    const bf16* __restrict__ hzg, const bf16* __restrict__ zhWt,
    const float* __restrict__ zhb, const int* __restrict__ seg,
    const int* __restrict__ cnts, const int* __restrict__ sids,
    float* __restrict__ out) {
  const int kb = blockIdx.z;
  const int cnt = cnts[kb];
  const int bm0 = blockIdx.y * 128;
  if (bm0 >= cnt) return;
  __shared__ bf16 As[128 * 32];  // 8 KB
  __shared__ bf16 Bs[64 * 32];   // 4 KB
  const int tid = threadIdx.x, lane = tid & 63, wid = tid >> 6;
  const int wm = wid >> 1, wn = wid & 1, quad = lane >> 4, l15 = lane & 15;
  const int n0 = blockIdx.x * 64;
  const int base = seg[kb];
  const int sr = tid >> 2, sc = (tid & 3) * 8;
  int r0i = bm0 + sr;      if (r0i >= cnt) r0i = cnt - 1;
  int r1i = bm0 + 64 + sr; if (r1i >= cnt) r1i = cnt - 1;
  const bf16* gA0 = hzg + (size_t)(base + r0i) * 1024 + sc;
  const bf16* gA1 = hzg + (size_t)(base + r1i) * 1024 + sc;
  const bf16* gB0 = zhWt + (size_t)kb * 512 * 1024 + (size_t)(n0 + sr) * 1024 + sc;
  bf16 *lA0 = &As[tid * 8], *lA1 = &As[2048 + tid * 8], *lB0 = &Bs[tid * 8];
  const bf16* aBase = &As[(wm * 64 + l15) * 32 + quad * 8];
  const bf16* bBase = &Bs[(wn * 32 + l15) * 32 + quad * 8];
  f32x4 acc[4][2] = {};
  for (int kt = 0; kt < 32; ++kt) {
    async16(gA0, lA0); async16(gA1, lA1); async16(gB0, lB0);
    gA0 += 32; gA1 += 32; gB0 += 32;
    __syncthreads();
    bf16x8 af[4], bfv[2];
#pragma unroll
    for (int r = 0; r < 4; ++r) af[r] = *(const bf16x8*)(aBase + r * 512);
#pragma unroll
    for (int c = 0; c < 2; ++c) bfv[c] = *(const bf16x8*)(bBase + c * 512);
#pragma unroll
    for (int r = 0; r < 4; ++r)
#pragma unroll
      for (int c = 0; c < 2; ++c)
        acc[r][c] = __builtin_amdgcn_mfma_f32_16x16x32_bf16(af[r], bfv[c], acc[r][c], 0, 0, 0);
    __syncthreads();
  }
  const float* bias = zhb + (size_t)kb * 512;
  float bv[2]; int gnn[2];
#pragma unroll
  for (int c = 0; c < 2; ++c) {
    gnn[c] = n0 + wn * 32 + c * 16 + l15;
    bv[c] = bias[gnn[c]];
  }
#pragma unroll
  for (int r = 0; r < 4; ++r)
#pragma unroll
    for (int q = 0; q < 4; ++q) {
      int lm = bm0 + wm * 64 + r * 16 + quad * 4 + q;
      if (lm < cnt) {
        int gm = sids[base + lm];
        size_t ob = (size_t)gm * 523 + 11;
#pragma unroll
        for (int c = 0; c < 2; ++c) {
          float v = acc[r][c][q] + bv[c];
          int n = gnn[c];
          out[ob + n] = (n < 256) ? fminf(fmaxf(v, -100.f), 100.f)
                                  : fminf(softplusf(v) + 0.001f, 100.f);
        }
      }
    }
}

// ---------------------------------------------------------------------------
// y/d heads from hyd[B][2048]
__global__ __launch_bounds__(256) void yd_head_k(
    const bf16* __restrict__ hyd, const int* __restrict__ t,
    const float* __restrict__ yhW, const float* __restrict__ yhb,
    const float* __restrict__ dhW, const float* __restrict__ dhb,
    float* __restrict__ out) {
  const int wv = threadIdx.x >> 6, lane = threadIdx.x & 63;
  const int b = blockIdx.x * 4 + wv;
  const int tb = t[b];
  const float* yW = yhW + (size_t)tb * 2048;
  const float* dW = dhW + (size_t)tb * 2048;
  float s0 = 0.f, s1 = 0.f, s2 = 0.f, s3 = 0.f;
  for (int i = lane; i < 1024; i += 64) {
    float a = __bfloat162float(hyd[(size_t)b * 2048 + i]);
    float c = __bfloat162float(hyd[(size_t)b * 2048 + 1024 + i]);
    s0 += a * yW[2 * i]; s1 += a * yW[2 * i + 1];
    s2 += c * dW[2 * i]; s3 += c * dW[2 * i + 1];
  }
#pragma unroll
  for (int off = 32; off > 0; off >>= 1) {
    s0 += __shfl_down(s0, off); s1 += __shfl_down(s1, off);
    s2 += __shfl_down(s2, off); s3 += __shfl_down(s3, off);
  }
  if (lane == 0) {
    size_t o = (size_t)b * 523;
    out[o + 7] = fminf(fmaxf(s0 + yhb[tb * 2], -1e6f), 1e6f);
    out[o + 8] = fminf(softplusf(s1 + yhb[tb * 2 + 1]) + 1e-3f, 1e6f);
    out[o + 9] = fminf(fmaxf(s2 + dhb[tb * 2], -1e6f), 1e6f);
    out[o + 10] = fminf(softplusf(s3 + dhb[tb * 2 + 1]) + 1e-3f, 1e6f);
  }
}

__global__ __launch_bounds__(256) void tlogits_k(
    const bf16* __restrict__ ht2, const float* __restrict__ tw2,
    const float* __restrict__ tb2, float* __restrict__ out) {
  const int wv = threadIdx.x >> 6, lane = threadIdx.x & 63;
  const int b = blockIdx.x * 4 + wv;
  float h[4];
#pragma unroll
  for (int j = 0; j < 4; ++j)
    h[j] = __bfloat162float(ht2[(size_t)b * 256 + lane * 4 + j]);
  float pp[7];
#pragma unroll
  for (int kk = 0; kk < 7; ++kk) {
    float s = 0.f;
#pragma unroll
    for (int j = 0; j < 4; ++j) s += h[j] * tw2[(lane * 4 + j) * 7 + kk];
    pp[kk] = s;
  }
#pragma unroll
  for (int kk = 0; kk < 7; ++kk)
#pragma unroll
    for (int off = 32; off > 0; off >>= 1) pp[kk] += __shfl_down(pp[kk], off);
  if (lane == 0) {
#pragma unroll
    for (int kk = 0; kk < 7; ++kk) {
      float v = eluf(pp[kk] + tb2[kk]);
      out[(size_t)b * 523 + kk] = fminf(fmaxf(v, -10.f), 10.f);
    }
  }
}

// ---------------------------------------------------------------------------
extern "C" void kernel_launch(void* const* d_in, const int* in_sizes, int n_in,
                              void* d_out, int out_size, void* d_ws, size_t ws_size,
                              hipStream_t stream) {
  const float* x   = (const float*)d_in[0];
  const int*   t   = (const int*)d_in[1];
  const float* yv  = (const float*)d_in[2];
  const float* dv  = (const float*)d_in[3];
  const float* tw0 = (const float*)d_in[4];
  const float* tb0 = (const float*)d_in[5];
  const float* tw1 = (const float*)d_in[6];
  const float* tb1 = (const float*)d_in[7];
  const float* tw2 = (const float*)d_in[8];
  const float* tb2 = (const float*)d_in[9];
  const float* yw0 = (const float*)d_in[10];
  const float* yb0 = (const float*)d_in[11];
  const float* yw1 = (const float*)d_in[12];
  const float* yb1 = (const float*)d_in[13];
  const float* yhW = (const float*)d_in[14];
  const float* yhb = (const float*)d_in[15];
  const float* dw0 = (const float*)d_in[16];
  const float* db0 = (const float*)d_in[17];
  const float* dw1 = (const float*)d_in[18];
  const float* db1 = (const float*)d_in[19];
  const float* dhW = (const float*)d_in[20];
  const float* dhb = (const float*)d_in[21];
  const float* zw0 = (const float*)d_in[22];
  const float* zb0 = (const float*)d_in[23];
  const float* zw1 = (const float*)d_in[24];
  const float* zb1 = (const float*)d_in[25];
  const float* zhW = (const float*)d_in[26];
  const float* zhb = (const float*)d_in[27];
  float* out = (float*)d_out;

  const int B = 16384;
  char* p = (char*)d_ws;
  auto take = [&](size_t bytes) {
    char* r = p;
    p += (bytes + 255) & ~(size_t)255;
    return r;
  };
  bf16*  BtL1    = (bf16*)take((size_t)3328 * 1024 * 2);
  bf16*  BtL2    = (bf16*)take((size_t)3072 * 1024 * 2);
  bf16*  tw1t    = (bf16*)take((size_t)256 * 256 * 2);
  bf16*  zhWt    = (bf16*)take((size_t)7 * 512 * 1024 * 2);
  float* biasAll = (float*)take(3328 * 4);
  float* r0All   = (float*)take(3328 * 4);
  float* r1All   = (float*)take(3328 * 4);
  float* biasL2  = (float*)take(3072 * 4);
  int*   cnt     = (int*)take(8 * 4);
  int*   seg     = (int*)take(8 * 4);
  int*   pos     = (int*)take((size_t)B * 4);
  int*   rank    = (int*)take((size_t)B * 4);
  int*   sids    = (int*)take((size_t)B * 4);
  bf16*  xb      = (bf16*)take((size_t)B * 1024 * 2);  // reused as hzg after L1
  bf16*  a1y     = (bf16*)take((size_t)B * 1024 * 2);  // reused as ht2 after L2
  bf16*  a1d     = (bf16*)take((size_t)B * 1024 * 2);
  bf16*  a1z     = (bf16*)take((size_t)B * 1024 * 2);
  bf16*  ht1     = (bf16*)take((size_t)B * 256 * 2);
  bf16*  hyd     = (bf16*)take((size_t)B * 2048 * 2);
  bf16*  hzg     = xb;
  bf16*  ht2     = a1y;

  // --- prep
  hipMemsetAsync(cnt, 0, 8 * 4, stream);
  bucketize_k<<<B / 256, 256, 0, stream>>>(t, cnt, pos);
  segk<<<1, 64, 0, stream>>>(cnt, seg);
  rankk<<<B / 256, 256, 0, stream>>>(t, pos, seg, rank, sids);
  cvt_x_k<<<(B * 1024) / (256 * 8), 256, 0, stream>>>(x, xb);
  trcvt4_k<<<dim3(32, 32, 4), 256, 0, stream>>>(yw0, dw0, zw0 + 2 * 1024, tw0, BtL1);
  trcvt3_k<<<dim3(32, 32, 3), 256, 0, stream>>>(yw1, dw1, zw1, BtL2);
  trcvt_k<<<dim3(8, 8, 1), 256, 0, stream>>>(tw1, tw1t, 256, 256);
  trcvt_k<<<dim3(16, 32, 7), 256, 0, stream>>>(zhW, zhWt, 1024, 512);
  biascat_k<<<13, 256, 0, stream>>>(yb0, db0, zb0, tb0, zw0, yb1, db1, zb1,
                                    biasAll, r0All, r1All, biasL2);
  // --- fused layer 1 (y0|d0|z0|t0), then fused layer 2 (y1|d1|z1 with hz permute)
  gemm_l1_k<<<dim3(26, 128), 256, 0, stream>>>(xb, BtL1, biasAll, r0All, r1All,
                                               yv, dv, a1y, a1d, a1z, ht1);
  gemm_l2_k<<<dim3(24, 128), 256, 0, stream>>>(a1y, a1d, a1z, BtL2, biasL2,
                                               hyd, hzg, rank);
  gemm_t1_k<<<dim3(2, 128), 256, 0, stream>>>(ht1, tw1t, tb1, ht2);
  // --- heads
  zhead_k<<<dim3(8, 24, 7), 256, 0, stream>>>(hzg, zhWt, zhb, seg, cnt, sids, out);
  yd_head_k<<<B / 4, 256, 0, stream>>>(hyd, t, yhW, yhb, dhW, dhb, out);
  tlogits_k<<<B / 4, 256, 0, stream>>>(ht2, tw2, tb2, out);
}

// Round 3
// 733.584 us; speedup vs baseline: 1.2337x; 1.0595x over previous
//
#include <hip/hip_runtime.h>
#include <hip/hip_bf16.h>
#include <cstdint>
#include <cstddef>

typedef __hip_bfloat16 bf16;
typedef __bf16 bf16x8 __attribute__((ext_vector_type(8)));
typedef float f32x4 __attribute__((ext_vector_type(4)));

#define DEVFN static __device__ __forceinline__

// async global->LDS, 16B per lane. LDS dest must be wave-uniform base + lane*16.
DEVFN void async16(const void* g, void* l) {
  __builtin_amdgcn_global_load_lds(
      (const __attribute__((address_space(1))) uint32_t*)g,
      (__attribute__((address_space(3))) uint32_t*)l, 16, 0, 0);
}

DEVFN float eluf(float v) { return v > 0.f ? v : expm1f(v); }
DEVFN float softplusf(float x) {
  return x > 0.f ? x + log1pf(expf(-x)) : log1pf(expf(x));
}

// ---------------------------------------------------------------------------
// shared 128x128-tile K-loop (BK=32, 4 waves 2x2, 4x4 frags of 16x16x32 bf16)
DEVFN void kloop(const bf16* gA0, const bf16* gA1, const bf16* gB0,
                 const bf16* gB1, bf16* lA0, bf16* lA1, bf16* lB0, bf16* lB1,
                 const bf16* aBase, const bf16* bBase, f32x4 (&acc)[4][4],
                 int kiters) {
  for (int kt = 0; kt < kiters; ++kt) {
    async16(gA0, lA0); async16(gA1, lA1);
    async16(gB0, lB0); async16(gB1, lB1);
    gA0 += 32; gA1 += 32; gB0 += 32; gB1 += 32;
    __syncthreads();
    bf16x8 af[4], bfv[4];
#pragma unroll
    for (int r = 0; r < 4; ++r) af[r] = *(const bf16x8*)(aBase + r * 512);
#pragma unroll
    for (int c = 0; c < 4; ++c) bfv[c] = *(const bf16x8*)(bBase + c * 512);
#pragma unroll
    for (int r = 0; r < 4; ++r)
#pragma unroll
      for (int c = 0; c < 4; ++c)
        acc[r][c] = __builtin_amdgcn_mfma_f32_16x16x32_bf16(af[r], bfv[c], acc[r][c], 0, 0, 0);
    __syncthreads();
  }
}

// ---------------------------------------------------------------------------
// prep: all transposes/converts/bias-concat in ONE launch, dispatch on blockIdx
DEVFN void transpose_tile(const float* src, bf16* dst, int R, int C, int bx, int by) {
  __shared__ float tile[32][33];
  const int c0 = bx * 32, r0 = by * 32;
  const int tx = threadIdx.x & 31, ty = threadIdx.x >> 5;
#pragma unroll
  for (int rr = ty; rr < 32; rr += 8)
    tile[rr][tx] = src[(size_t)(r0 + rr) * C + c0 + tx];
  __syncthreads();
#pragma unroll
  for (int rr = ty; rr < 32; rr += 8)
    dst[(size_t)(c0 + rr) * R + r0 + tx] = __float2bfloat16(tile[tx][rr]);
}

__global__ __launch_bounds__(256) void prep_all_k(
    const float* __restrict__ x, bf16* __restrict__ xb,
    const float* __restrict__ yw0, const float* __restrict__ dw0,
    const float* __restrict__ zw0, const float* __restrict__ tw0,
    bf16* __restrict__ BtL1,
    const float* __restrict__ yw1, const float* __restrict__ dw1,
    const float* __restrict__ zw1, bf16* __restrict__ BtL2,
    const float* __restrict__ tw1, bf16* __restrict__ tw1t,
    const float* __restrict__ zhW, bf16* __restrict__ zhWt,
    const float* __restrict__ yb0, const float* __restrict__ db0,
    const float* __restrict__ zb0, const float* __restrict__ tb0,
    const float* __restrict__ yb1, const float* __restrict__ db1,
    const float* __restrict__ zb1,
    float* __restrict__ biasAll, float* __restrict__ r0All,
    float* __restrict__ r1All, float* __restrict__ biasL2) {
  int l = blockIdx.x;
  if (l < 8192) {  // x fp32 -> bf16, 8 elems/thread
    size_t i = ((size_t)l * 256 + threadIdx.x) * 8;
    float4 v0 = *(const float4*)(x + i);
    float4 v1 = *(const float4*)(x + i + 4);
    union { bf16 h[8]; uint4 u; } o;
    o.h[0] = __float2bfloat16(v0.x); o.h[1] = __float2bfloat16(v0.y);
    o.h[2] = __float2bfloat16(v0.z); o.h[3] = __float2bfloat16(v0.w);
    o.h[4] = __float2bfloat16(v1.x); o.h[5] = __float2bfloat16(v1.y);
    o.h[6] = __float2bfloat16(v1.z); o.h[7] = __float2bfloat16(v1.w);
    *(uint4*)(xb + i) = o.u;
    return;
  }
  l -= 8192;
  if (l < 4096) {  // BtL1: {yw0,dw0,zw0[2:],tw0} transposed
    int z = l >> 10, rem = l & 1023, bx = rem & 31, by = rem >> 5;
    const float* src = (z == 0) ? yw0 : (z == 1) ? dw0 : (z == 2) ? zw0 + 2048 : tw0;
    int C = (z == 3) ? 256 : 1024;
    if (bx * 32 < C)
      transpose_tile(src, BtL1 + (size_t)z * 1024 * 1024, 1024, C, bx, by);
    return;
  }
  l -= 4096;
  if (l < 3072) {  // BtL2: {yw1,dw1,zw1} transposed
    int z = l >> 10, rem = l & 1023, bx = rem & 31, by = rem >> 5;
    const float* src = (z == 0) ? yw1 : (z == 1) ? dw1 : zw1;
    transpose_tile(src, BtL2 + (size_t)z * 1024 * 1024, 1024, 1024, bx, by);
    return;
  }
  l -= 3072;
  if (l < 64) {  // tw1t
    transpose_tile(tw1, tw1t, 256, 256, l & 7, l >> 3);
    return;
  }
  l -= 64;
  if (l < 3584) {  // zhWt: 7 x [1024][512] -> [512][1024]
    int z = l >> 9, rem = l & 511, bx = rem & 15, by = rem >> 4;
    transpose_tile(zhW + (size_t)z * 1024 * 512, zhWt + (size_t)z * 512 * 1024,
                   1024, 512, bx, by);
    return;
  }
  l -= 3584;
  {  // bias / rank-2 concat
    int i = l * 256 + threadIdx.x;
    if (i >= 3328) return;
    float b;
    if (i < 1024) b = yb0[i];
    else if (i < 2048) b = db0[i - 1024];
    else if (i < 3072) b = zb0[i - 2048];
    else b = tb0[i - 3072];
    biasAll[i] = b;
    bool inz = (i >= 2048 && i < 3072);
    r0All[i] = inz ? zw0[i - 2048] : 0.f;
    r1All[i] = inz ? zw0[1024 + (i - 2048)] : 0.f;
    if (i < 3072)
      biasL2[i] = (i < 1024) ? yb1[i] : (i < 2048) ? db1[i - 1024] : zb1[i - 2048];
  }
}

// bucket bookkeeping
__global__ __launch_bounds__(256) void bucketize_k(const int* __restrict__ t,
                                                   int* __restrict__ cnt,
                                                   int* __restrict__ pos) {
  int b = blockIdx.x * 256 + threadIdx.x;
  pos[b] = atomicAdd(&cnt[t[b]], 1);
}
__global__ void segk(const int* __restrict__ cnt, int* __restrict__ seg) {
  if (threadIdx.x == 0) {
    int s = 0;
    for (int k = 0; k < 7; ++k) { seg[k] = s; s += cnt[k]; }
    seg[7] = s;
  }
}
__global__ __launch_bounds__(256) void rankk(const int* __restrict__ t,
                                             const int* __restrict__ pos,
                                             const int* __restrict__ seg,
                                             int* __restrict__ rank,
                                             int* __restrict__ sids) {
  int b = blockIdx.x * 256 + threadIdx.x;
  int r = seg[t[b]] + pos[b];
  rank[b] = r;
  sids[r] = b;
}

// ---------------------------------------------------------------------------
// fused layer-1: [16384,1024] x [1024,3328] -> {a1y,a1d,a1z,ht1}
// XCD-swizzled 1D grid: each XCD owns a 16-m-tile stripe (two 8-m passes),
// n-major within a pass -> A working set 2 MB/XCD stays L2-resident.
__global__ __launch_bounds__(256) void gemm_l1_k(
    const bf16* __restrict__ A, const bf16* __restrict__ Bt,
    const float* __restrict__ biasAll, const float* __restrict__ r0All,
    const float* __restrict__ r1All, const float* __restrict__ yv,
    const float* __restrict__ dv, bf16* __restrict__ a1y,
    bf16* __restrict__ a1d, bf16* __restrict__ a1z, bf16* __restrict__ ht1) {
  __shared__ bf16 As[128 * 32];
  __shared__ bf16 Bs[128 * 32];
  const int tid = threadIdx.x, lane = tid & 63, wid = tid >> 6;
  const int wm = wid >> 1, wn = wid & 1, quad = lane >> 4, l15 = lane & 15;
  const int id = blockIdx.x;
  const int xcd = id & 7, lid = id >> 3;          // lid in [0,416)
  const int pass = lid / 208, rem = lid - pass * 208;  // 208 = 8m x 26n
  const int mt = xcd * 16 + pass * 8 + (rem & 7), nt = rem >> 3;
  const int bm0 = mt * 128, bn0 = nt * 128;
  const int sr = tid >> 2, sc = (tid & 3) * 8;
  f32x4 acc[4][4] = {};
  kloop(A + (size_t)(bm0 + sr) * 1024 + sc,
        A + (size_t)(bm0 + 64 + sr) * 1024 + sc,
        Bt + (size_t)(bn0 + sr) * 1024 + sc,
        Bt + (size_t)(bn0 + 64 + sr) * 1024 + sc,
        &As[tid * 8], &As[2048 + tid * 8], &Bs[tid * 8], &Bs[2048 + tid * 8],
        &As[(wm * 64 + l15) * 32 + quad * 8],
        &Bs[(wn * 64 + l15) * 32 + quad * 8], acc, 32);
  const int g = nt >> 3;
  bf16* dst = (g == 0) ? a1y : (g == 1) ? a1d : (g == 2) ? a1z : ht1;
  const int ldc = (g == 3) ? 256 : 1024;
  const int colb = bn0 - g * 1024;
  float bv[4], z0[4], z1[4];
#pragma unroll
  for (int c = 0; c < 4; ++c) {
    int gn = bn0 + wn * 64 + c * 16 + l15;
    bv[c] = biasAll[gn]; z0[c] = r0All[gn]; z1[c] = r1All[gn];
  }
#pragma unroll
  for (int r = 0; r < 4; ++r) {
#pragma unroll
    for (int q = 0; q < 4; ++q) {
      int gm = bm0 + wm * 64 + r * 16 + quad * 4 + q;
      float yy = yv[gm], dd = dv[gm];
#pragma unroll
      for (int c = 0; c < 4; ++c) {
        float v = acc[r][c][q] + bv[c] + yy * z0[c] + dd * z1[c];
        dst[(size_t)gm * ldc + colb + wn * 64 + c * 16 + l15] = __float2bfloat16(eluf(v));
      }
    }
  }
}

// fused layer-2 + t-layer-2: blocks [0,3072) = y1|d1|z1 (K=1024, XCD-swizzled),
// blocks [3072,3328) = t1 (K=256). hz rows written permuted via rank[].
__global__ __launch_bounds__(256) void gemm_l2t_k(
    const bf16* __restrict__ a1y, const bf16* __restrict__ a1d,
    const bf16* __restrict__ a1z, const bf16* __restrict__ ht1,
    const bf16* __restrict__ BtL2, const bf16* __restrict__ tw1t,
    const float* __restrict__ biasL2, const float* __restrict__ tb1,
    bf16* __restrict__ hyd, bf16* __restrict__ hzg, bf16* __restrict__ ht2,
    const int* __restrict__ rank) {
  __shared__ bf16 As[128 * 32];
  __shared__ bf16 Bs[128 * 32];
  const int tid = threadIdx.x, lane = tid & 63, wid = tid >> 6;
  const int wm = wid >> 1, wn = wid & 1, quad = lane >> 4, l15 = lane & 15;
  const int id = blockIdx.x;
  int bm0, bn0, Ka, g;
  const bf16 *Aptr, *Bptr;
  if (id < 3072) {
    const int xcd = id & 7, lid = id >> 3;          // lid in [0,384)
    const int pass = lid / 192, rem = lid - pass * 192;  // 192 = 8m x 24n
    const int mt = xcd * 16 + pass * 8 + (rem & 7), nt = rem >> 3;
    bm0 = mt * 128; bn0 = nt * 128; Ka = 1024;
    g = nt >> 3;
    Aptr = (g == 0) ? a1y : (g == 1) ? a1d : a1z;
    Bptr = BtL2;
  } else {
    const int local = id - 3072;
    bm0 = (local >> 1) * 128; bn0 = (local & 1) * 128; Ka = 256;
    g = 3; Aptr = ht1; Bptr = tw1t;
  }
  const int sr = tid >> 2, sc = (tid & 3) * 8;
  f32x4 acc[4][4] = {};
  kloop(Aptr + (size_t)(bm0 + sr) * Ka + sc,
        Aptr + (size_t)(bm0 + 64 + sr) * Ka + sc,
        Bptr + (size_t)(bn0 + sr) * Ka + sc,
        Bptr + (size_t)(bn0 + 64 + sr) * Ka + sc,
        &As[tid * 8], &As[2048 + tid * 8], &Bs[tid * 8], &Bs[2048 + tid * 8],
        &As[(wm * 64 + l15) * 32 + quad * 8],
        &Bs[(wn * 64 + l15) * 32 + quad * 8], acc, Ka >> 5);
  const float* bias = (g == 3) ? tb1 : biasL2;
  float bv[4];
#pragma unroll
  for (int c = 0; c < 4; ++c) bv[c] = bias[bn0 + wn * 64 + c * 16 + l15];
#pragma unroll
  for (int r = 0; r < 4; ++r) {
#pragma unroll
    for (int q = 0; q < 4; ++q) {
      int gm = bm0 + wm * 64 + r * 16 + quad * 4 + q;
      bf16* dst; size_t rowoff;
      if (g == 2) { dst = hzg; rowoff = (size_t)rank[gm] * 1024 + (size_t)(bn0 - 2048); }
      else if (g == 3) { dst = ht2; rowoff = (size_t)gm * 256 + bn0; }
      else { dst = hyd; rowoff = (size_t)gm * 2048 + bn0; }
#pragma unroll
      for (int c = 0; c < 4; ++c) {
        float v = acc[r][c][q] + bv[c];
        dst[rowoff + wn * 64 + c * 16 + l15] = __float2bfloat16(eluf(v));
      }
    }
  }
}

// ---------------------------------------------------------------------------
// z-head: per-bucket GEMM on permuted contiguous rows, 128x64 tiles.
__global__ __launch_bounds__(256) void zhead_k(
    const bf16* __restrict__ hzg, const bf16* __restrict__ zhWt,
    const float* __restrict__ zhb, const int* __restrict__ seg,
    const int* __restrict__ cnts, const int* __restrict__ sids,
    float* __restrict__ out) {
  const int kb = blockIdx.z;
  const int cnt = cnts[kb];
  const int bm0 = blockIdx.y * 128;
  if (bm0 >= cnt) return;
  __shared__ bf16 As[128 * 32];  // 8 KB
  __shared__ bf16 Bs[64 * 32];   // 4 KB
  const int tid = threadIdx.x, lane = tid & 63, wid = tid >> 6;
  const int wm = wid >> 1, wn = wid & 1, quad = lane >> 4, l15 = lane & 15;
  const int n0 = blockIdx.x * 64;
  const int base = seg[kb];
  const int sr = tid >> 2, sc = (tid & 3) * 8;
  int r0i = bm0 + sr;      if (r0i >= cnt) r0i = cnt - 1;
  int r1i = bm0 + 64 + sr; if (r1i >= cnt) r1i = cnt - 1;
  const bf16* gA0 = hzg + (size_t)(base + r0i) * 1024 + sc;
  const bf16* gA1 = hzg + (size_t)(base + r1i) * 1024 + sc;
  const bf16* gB0 = zhWt + (size_t)kb * 512 * 1024 + (size_t)(n0 + sr) * 1024 + sc;
  bf16 *lA0 = &As[tid * 8], *lA1 = &As[2048 + tid * 8], *lB0 = &Bs[tid * 8];
  const bf16* aBase = &As[(wm * 64 + l15) * 32 + quad * 8];
  const bf16* bBase = &Bs[(wn * 32 + l15) * 32 + quad * 8];
  f32x4 acc[4][2] = {};
  for (int kt = 0; kt < 32; ++kt) {
    async16(gA0, lA0); async16(gA1, lA1); async16(gB0, lB0);
    gA0 += 32; gA1 += 32; gB0 += 32;
    __syncthreads();
    bf16x8 af[4], bfv[2];
#pragma unroll
    for (int r = 0; r < 4; ++r) af[r] = *(const bf16x8*)(aBase + r * 512);
#pragma unroll
    for (int c = 0; c < 2; ++c) bfv[c] = *(const bf16x8*)(bBase + c * 512);
#pragma unroll
    for (int r = 0; r < 4; ++r)
#pragma unroll
      for (int c = 0; c < 2; ++c)
        acc[r][c] = __builtin_amdgcn_mfma_f32_16x16x32_bf16(af[r], bfv[c], acc[r][c], 0, 0, 0);
    __syncthreads();
  }
  const float* bias = zhb + (size_t)kb * 512;
  float bv[2]; int gnn[2];
#pragma unroll
  for (int c = 0; c < 2; ++c) {
    gnn[c] = n0 + wn * 32 + c * 16 + l15;
    bv[c] = bias[gnn[c]];
  }
#pragma unroll
  for (int r = 0; r < 4; ++r)
#pragma unroll
    for (int q = 0; q < 4; ++q) {
      int lm = bm0 + wm * 64 + r * 16 + quad * 4 + q;
      if (lm < cnt) {
        int gm = sids[base + lm];
        size_t ob = (size_t)gm * 523 + 11;
#pragma unroll
        for (int c = 0; c < 2; ++c) {
          float v = acc[r][c][q] + bv[c];
          int n = gnn[c];
          out[ob + n] = (n < 256) ? fminf(fmaxf(v, -100.f), 100.f)
                                  : fminf(softplusf(v) + 0.001f, 100.f);
        }
      }
    }
}

// ---------------------------------------------------------------------------
// merged y/d heads + t-logits
__global__ __launch_bounds__(256) void heads_k(
    const bf16* __restrict__ hyd, const bf16* __restrict__ ht2,
    const int* __restrict__ t, const float* __restrict__ yhW,
    const float* __restrict__ yhb, const float* __restrict__ dhW,
    const float* __restrict__ dhb, const float* __restrict__ tw2,
    const float* __restrict__ tb2, float* __restrict__ out) {
  const int wv = threadIdx.x >> 6, lane = threadIdx.x & 63;
  if (blockIdx.x < 4096) {
    const int b = blockIdx.x * 4 + wv;
    const int tb = t[b];
    const float* yW = yhW + (size_t)tb * 2048;
    const float* dW = dhW + (size_t)tb * 2048;
    float s0 = 0.f, s1 = 0.f, s2 = 0.f, s3 = 0.f;
    for (int i = lane; i < 1024; i += 64) {
      float a = __bfloat162float(hyd[(size_t)b * 2048 + i]);
      float c = __bfloat162float(hyd[(size_t)b * 2048 + 1024 + i]);
      s0 += a * yW[2 * i]; s1 += a * yW[2 * i + 1];
      s2 += c * dW[2 * i]; s3 += c * dW[2 * i + 1];
    }
#pragma unroll
    for (int off = 32; off > 0; off >>= 1) {
      s0 += __shfl_down(s0, off); s1 += __shfl_down(s1, off);
      s2 += __shfl_down(s2, off); s3 += __shfl_down(s3, off);
    }
    if (lane == 0) {
      size_t o = (size_t)b * 523;
      out[o + 7] = fminf(fmaxf(s0 + yhb[tb * 2], -1e6f), 1e6f);
      out[o + 8] = fminf(softplusf(s1 + yhb[tb * 2 + 1]) + 1e-3f, 1e6f);
      out[o + 9] = fminf(fmaxf(s2 + dhb[tb * 2], -1e6f), 1e6f);
      out[o + 10] = fminf(softplusf(s3 + dhb[tb * 2 + 1]) + 1e-3f, 1e6f);
    }
  } else {
    const int b = (blockIdx.x - 4096) * 4 + wv;
    float h[4];
#pragma unroll
    for (int j = 0; j < 4; ++j)
      h[j] = __bfloat162float(ht2[(size_t)b * 256 + lane * 4 + j]);
    float pp[7];
#pragma unroll
    for (int kk = 0; kk < 7; ++kk) {
      float s = 0.f;
#pragma unroll
      for (int j = 0; j < 4; ++j) s += h[j] * tw2[(lane * 4 + j) * 7 + kk];
      pp[kk] = s;
    }
#pragma unroll
    for (int kk = 0; kk < 7; ++kk)
#pragma unroll
      for (int off = 32; off > 0; off >>= 1) pp[kk] += __shfl_down(pp[kk], off);
    if (lane == 0) {
#pragma unroll
      for (int kk = 0; kk < 7; ++kk) {
        float v = eluf(pp[kk] + tb2[kk]);
        out[(size_t)b * 523 + kk] = fminf(fmaxf(v, -10.f), 10.f);
      }
    }
  }
}

// ---------------------------------------------------------------------------
extern "C" void kernel_launch(void* const* d_in, const int* in_sizes, int n_in,
                              void* d_out, int out_size, void* d_ws, size_t ws_size,
                              hipStream_t stream) {
  const float* x   = (const float*)d_in[0];
  const int*   t   = (const int*)d_in[1];
  const float* yv  = (const float*)d_in[2];
  const float* dv  = (const float*)d_in[3];
  const float* tw0 = (const float*)d_in[4];
  const float* tb0 = (const float*)d_in[5];
  const float* tw1 = (const float*)d_in[6];
  const float* tb1 = (const float*)d_in[7];
  const float* tw2 = (const float*)d_in[8];
  const float* tb2 = (const float*)d_in[9];
  const float* yw0 = (const float*)d_in[10];
  const float* yb0 = (const float*)d_in[11];
  const float* yw1 = (const float*)d_in[12];
  const float* yb1 = (const float*)d_in[13];
  const float* yhW = (const float*)d_in[14];
  const float* yhb = (const float*)d_in[15];
  const float* dw0 = (const float*)d_in[16];
  const float* db0 = (const float*)d_in[17];
  const float* dw1 = (const float*)d_in[18];
  const float* db1 = (const float*)d_in[19];
  const float* dhW = (const float*)d_in[20];
  const float* dhb = (const float*)d_in[21];
  const float* zw0 = (const float*)d_in[22];
  const float* zb0 = (const float*)d_in[23];
  const float* zw1 = (const float*)d_in[24];
  const float* zb1 = (const float*)d_in[25];
  const float* zhW = (const float*)d_in[26];
  const float* zhb = (const float*)d_in[27];
  float* out = (float*)d_out;

  const int B = 16384;
  char* p = (char*)d_ws;
  auto take = [&](size_t bytes) {
    char* r = p;
    p += (bytes + 255) & ~(size_t)255;
    return r;
  };
  bf16*  BtL1    = (bf16*)take((size_t)3328 * 1024 * 2);
  bf16*  BtL2    = (bf16*)take((size_t)3072 * 1024 * 2);
  bf16*  tw1t    = (bf16*)take((size_t)256 * 256 * 2);
  bf16*  zhWt    = (bf16*)take((size_t)7 * 512 * 1024 * 2);
  float* biasAll = (float*)take(3328 * 4);
  float* r0All   = (float*)take(3328 * 4);
  float* r1All   = (float*)take(3328 * 4);
  float* biasL2  = (float*)take(3072 * 4);
  int*   cnt     = (int*)take(8 * 4);
  int*   seg     = (int*)take(8 * 4);
  int*   pos     = (int*)take((size_t)B * 4);
  int*   rank    = (int*)take((size_t)B * 4);
  int*   sids    = (int*)take((size_t)B * 4);
  bf16*  xb      = (bf16*)take((size_t)B * 1024 * 2);  // reused as hzg after L1
  bf16*  a1y     = (bf16*)take((size_t)B * 1024 * 2);
  bf16*  a1d     = (bf16*)take((size_t)B * 1024 * 2);
  bf16*  a1z     = (bf16*)take((size_t)B * 1024 * 2);
  bf16*  ht1     = (bf16*)take((size_t)B * 256 * 2);
  bf16*  hyd     = (bf16*)take((size_t)B * 2048 * 2);
  bf16*  ht2     = (bf16*)take((size_t)B * 256 * 2);
  bf16*  hzg     = xb;

  hipMemsetAsync(cnt, 0, 8 * 4, stream);
  bucketize_k<<<B / 256, 256, 0, stream>>>(t, cnt, pos);
  segk<<<1, 64, 0, stream>>>(cnt, seg);
  rankk<<<B / 256, 256, 0, stream>>>(t, pos, seg, rank, sids);
  prep_all_k<<<19021, 256, 0, stream>>>(x, xb, yw0, dw0, zw0, tw0, BtL1,
                                        yw1, dw1, zw1, BtL2, tw1, tw1t, zhW, zhWt,
                                        yb0, db0, zb0, tb0, yb1, db1, zb1,
                                        biasAll, r0All, r1All, biasL2);
  gemm_l1_k<<<3328, 256, 0, stream>>>(xb, BtL1, biasAll, r0All, r1All,
                                      yv, dv, a1y, a1d, a1z, ht1);
  gemm_l2t_k<<<3328, 256, 0, stream>>>(a1y, a1d, a1z, ht1, BtL2, tw1t,
                                       biasL2, tb1, hyd, hzg, ht2, rank);
  zhead_k<<<dim3(8, 24, 7), 256, 0, stream>>>(hzg, zhWt, zhb, seg, cnt, sids, out);
  heads_k<<<8192, 256, 0, stream>>>(hyd, ht2, t, yhW, yhb, dhW, dhb, tw2, tb2, out);
}

// Round 4
// 703.007 us; speedup vs baseline: 1.2874x; 1.0435x over previous
//
#include <hip/hip_runtime.h>
#include <hip/hip_bf16.h>
#include <cstdint>
#include <cstddef>

typedef __hip_bfloat16 bf16;
typedef __bf16 bf16x8 __attribute__((ext_vector_type(8)));
typedef float f32x4 __attribute__((ext_vector_type(4)));

#define DEVFN static __device__ __forceinline__

// async global->LDS, 16B per lane. LDS dest must be wave-uniform base + lane*16.
DEVFN void async16(const void* g, void* l) {
  __builtin_amdgcn_global_load_lds(
      (const __attribute__((address_space(1))) uint32_t*)g,
      (__attribute__((address_space(3))) uint32_t*)l, 16, 0, 0);
}

DEVFN float eluf(float v) { return v > 0.f ? v : expm1f(v); }
DEVFN float softplusf(float x) {
  return x > 0.f ? x + log1pf(expf(-x)) : log1pf(expf(x));
}

// ---------------------------------------------------------------------------
// BK=64 XOR-swizzled K-loop. A tile 128x64, B tile (NCHB*32)x64.
// LDS slot (row, g) holds global (row, g ^ (row&7)); staging applies the
// swizzle on the GLOBAL address (LDS dest is pinned to lane*16), fragment
// reads apply it on the LDS side -> ds_read_b128 banks are 2-way (free).
template <int NCHB, int NFB>
DEVFN void kloop64(const bf16* (&gA)[4], const bf16* (&gB)[NCHB], bf16* As,
                   bf16* Bs, int tid, const bf16* aBase, const bf16* bBase,
                   const int (&colsel)[2], f32x4 (&acc)[4][NFB], int kiters) {
  for (int kt = 0; kt < kiters; ++kt) {
#pragma unroll
    for (int c = 0; c < 4; ++c) async16(gA[c], As + c * 2048 + tid * 8);
#pragma unroll
    for (int c = 0; c < NCHB; ++c) async16(gB[c], Bs + c * 2048 + tid * 8);
#pragma unroll
    for (int c = 0; c < 4; ++c) gA[c] += 64;
#pragma unroll
    for (int c = 0; c < NCHB; ++c) gB[c] += 64;
    __syncthreads();
#pragma unroll
    for (int s = 0; s < 2; ++s) {
      bf16x8 af[4], bfv[NFB];
#pragma unroll
      for (int r = 0; r < 4; ++r)
        af[r] = *(const bf16x8*)(aBase + r * 1024 + colsel[s]);
#pragma unroll
      for (int c = 0; c < NFB; ++c)
        bfv[c] = *(const bf16x8*)(bBase + c * 1024 + colsel[s]);
#pragma unroll
      for (int r = 0; r < 4; ++r)
#pragma unroll
        for (int c = 0; c < NFB; ++c)
          acc[r][c] = __builtin_amdgcn_mfma_f32_16x16x32_bf16(af[r], bfv[c], acc[r][c], 0, 0, 0);
    }
    __syncthreads();
  }
}

// ---------------------------------------------------------------------------
// prep: all transposes/converts/bias-concat in ONE launch, dispatch on blockIdx
DEVFN void transpose_tile(const float* src, bf16* dst, int R, int C, int bx, int by) {
  __shared__ float tile[32][33];
  const int c0 = bx * 32, r0 = by * 32;
  const int tx = threadIdx.x & 31, ty = threadIdx.x >> 5;
#pragma unroll
  for (int rr = ty; rr < 32; rr += 8)
    tile[rr][tx] = src[(size_t)(r0 + rr) * C + c0 + tx];
  __syncthreads();
#pragma unroll
  for (int rr = ty; rr < 32; rr += 8)
    dst[(size_t)(c0 + rr) * R + r0 + tx] = __float2bfloat16(tile[tx][rr]);
}

__global__ __launch_bounds__(256) void prep_all_k(
    const float* __restrict__ x, bf16* __restrict__ xb,
    const float* __restrict__ yw0, const float* __restrict__ dw0,
    const float* __restrict__ zw0, const float* __restrict__ tw0,
    bf16* __restrict__ BtL1,
    const float* __restrict__ yw1, const float* __restrict__ dw1,
    const float* __restrict__ zw1, bf16* __restrict__ BtL2,
    const float* __restrict__ tw1, bf16* __restrict__ tw1t,
    const float* __restrict__ zhW, bf16* __restrict__ zhWt,
    const float* __restrict__ yb0, const float* __restrict__ db0,
    const float* __restrict__ zb0, const float* __restrict__ tb0,
    const float* __restrict__ yb1, const float* __restrict__ db1,
    const float* __restrict__ zb1,
    float* __restrict__ biasAll, float* __restrict__ r0All,
    float* __restrict__ r1All, float* __restrict__ biasL2) {
  int l = blockIdx.x;
  if (l < 8192) {  // x fp32 -> bf16, 8 elems/thread
    size_t i = ((size_t)l * 256 + threadIdx.x) * 8;
    float4 v0 = *(const float4*)(x + i);
    float4 v1 = *(const float4*)(x + i + 4);
    union { bf16 h[8]; uint4 u; } o;
    o.h[0] = __float2bfloat16(v0.x); o.h[1] = __float2bfloat16(v0.y);
    o.h[2] = __float2bfloat16(v0.z); o.h[3] = __float2bfloat16(v0.w);
    o.h[4] = __float2bfloat16(v1.x); o.h[5] = __float2bfloat16(v1.y);
    o.h[6] = __float2bfloat16(v1.z); o.h[7] = __float2bfloat16(v1.w);
    *(uint4*)(xb + i) = o.u;
    return;
  }
  l -= 8192;
  if (l < 4096) {  // BtL1: {yw0,dw0,zw0[2:],tw0} transposed
    int z = l >> 10, rem = l & 1023, bx = rem & 31, by = rem >> 5;
    const float* src = (z == 0) ? yw0 : (z == 1) ? dw0 : (z == 2) ? zw0 + 2048 : tw0;
    int C = (z == 3) ? 256 : 1024;
    if (bx * 32 < C)
      transpose_tile(src, BtL1 + (size_t)z * 1024 * 1024, 1024, C, bx, by);
    return;
  }
  l -= 4096;
  if (l < 3072) {  // BtL2: {yw1,dw1,zw1} transposed
    int z = l >> 10, rem = l & 1023, bx = rem & 31, by = rem >> 5;
    const float* src = (z == 0) ? yw1 : (z == 1) ? dw1 : zw1;
    transpose_tile(src, BtL2 + (size_t)z * 1024 * 1024, 1024, 1024, bx, by);
    return;
  }
  l -= 3072;
  if (l < 64) {  // tw1t
    transpose_tile(tw1, tw1t, 256, 256, l & 7, l >> 3);
    return;
  }
  l -= 64;
  if (l < 3584) {  // zhWt: 7 x [1024][512] -> [512][1024]
    int z = l >> 9, rem = l & 511, bx = rem & 15, by = rem >> 4;
    transpose_tile(zhW + (size_t)z * 1024 * 512, zhWt + (size_t)z * 512 * 1024,
                   1024, 512, bx, by);
    return;
  }
  l -= 3584;
  {  // bias / rank-2 concat
    int i = l * 256 + threadIdx.x;
    if (i >= 3328) return;
    float b;
    if (i < 1024) b = yb0[i];
    else if (i < 2048) b = db0[i - 1024];
    else if (i < 3072) b = zb0[i - 2048];
    else b = tb0[i - 3072];
    biasAll[i] = b;
    bool inz = (i >= 2048 && i < 3072);
    r0All[i] = inz ? zw0[i - 2048] : 0.f;
    r1All[i] = inz ? zw0[1024 + (i - 2048)] : 0.f;
    if (i < 3072)
      biasL2[i] = (i < 1024) ? yb1[i] : (i < 2048) ? db1[i - 1024] : zb1[i - 2048];
  }
}

// ---------------------------------------------------------------------------
// single-block bucket bookkeeping: histogram + seg + rank + sids in one launch
__global__ __launch_bounds__(1024) void book_k(const int* __restrict__ t,
                                               int* __restrict__ cnt,
                                               int* __restrict__ seg,
                                               int* __restrict__ rank,
                                               int* __restrict__ sids) {
  __shared__ int h[8], sseg[8];
  const int tid = threadIdx.x;
  if (tid < 8) h[tid] = 0;
  __syncthreads();
  int tv[16], lc[7] = {0, 0, 0, 0, 0, 0, 0};
  const int base = tid * 16;
#pragma unroll
  for (int i = 0; i < 16; ++i) { tv[i] = t[base + i]; lc[tv[i]]++; }
  int myoff[7];
#pragma unroll
  for (int k = 0; k < 7; ++k) myoff[k] = atomicAdd(&h[k], lc[k]);
  __syncthreads();
  if (tid == 0) {
    int s = 0;
    for (int k = 0; k < 7; ++k) { sseg[k] = s; s += h[k]; }
    sseg[7] = s;
  }
  __syncthreads();
  if (tid < 7) { cnt[tid] = h[tid]; seg[tid] = sseg[tid]; }
  if (tid == 7) seg[7] = sseg[7];
  int cur[7];
#pragma unroll
  for (int k = 0; k < 7; ++k) cur[k] = sseg[k] + myoff[k];
#pragma unroll
  for (int i = 0; i < 16; ++i) {
    int b = base + i, k = tv[i];
    int r = cur[k]++;
    rank[b] = r;
    sids[r] = b;
  }
}

// ---------------------------------------------------------------------------
// fused layer-1: [16384,1024] x [1024,3328] -> {a1y,a1d,a1z,ht1}
// XCD-swizzled 1D grid; BK=64 swizzled k-loop.
__global__ __launch_bounds__(256) void gemm_l1_k(
    const bf16* __restrict__ A, const bf16* __restrict__ Bt,
    const float* __restrict__ biasAll, const float* __restrict__ r0All,
    const float* __restrict__ r1All, const float* __restrict__ yv,
    const float* __restrict__ dv, bf16* __restrict__ a1y,
    bf16* __restrict__ a1d, bf16* __restrict__ a1z, bf16* __restrict__ ht1) {
  __shared__ bf16 As[128 * 64];
  __shared__ bf16 Bs[128 * 64];
  const int tid = threadIdx.x, lane = tid & 63, wid = tid >> 6;
  const int wm = wid >> 1, wn = wid & 1, quad = lane >> 4, l15 = lane & 15;
  const int id = blockIdx.x;
  const int xcd = id & 7, lid = id >> 3;               // lid in [0,416)
  const int pass = lid / 208, rem = lid - pass * 208;  // 208 = 8m x 26n
  const int mt = xcd * 16 + pass * 8 + (rem & 7), nt = rem >> 3;
  const int bm0 = mt * 128, bn0 = nt * 128;
  const int sr3 = tid >> 3, scol = ((tid & 7) ^ (sr3 & 7)) * 8;
  const bf16* gA[4];
  const bf16* gB[4];
#pragma unroll
  for (int c = 0; c < 4; ++c) {
    gA[c] = A + (size_t)(bm0 + c * 32 + sr3) * 1024 + scol;
    gB[c] = Bt + (size_t)(bn0 + c * 32 + sr3) * 1024 + scol;
  }
  const bf16* aBase = &As[(wm * 64 + l15) * 64];
  const bf16* bBase = &Bs[(wn * 64 + l15) * 64];
  int colsel[2];
#pragma unroll
  for (int s = 0; s < 2; ++s) colsel[s] = ((s * 4 + quad) ^ (l15 & 7)) * 8;
  f32x4 acc[4][4] = {};
  kloop64<4, 4>(gA, gB, As, Bs, tid, aBase, bBase, colsel, acc, 16);

  const int g = nt >> 3;
  bf16* dst = (g == 0) ? a1y : (g == 1) ? a1d : (g == 2) ? a1z : ht1;
  const int ldc = (g == 3) ? 256 : 1024;
  const int colb = bn0 - g * 1024;
  float bv[4], z0[4], z1[4];
#pragma unroll
  for (int c = 0; c < 4; ++c) {
    int gn = bn0 + wn * 64 + c * 16 + l15;
    bv[c] = biasAll[gn]; z0[c] = r0All[gn]; z1[c] = r1All[gn];
  }
#pragma unroll
  for (int r = 0; r < 4; ++r) {
#pragma unroll
    for (int q = 0; q < 4; ++q) {
      int gm = bm0 + wm * 64 + r * 16 + quad * 4 + q;
      float yy = yv[gm], dd = dv[gm];
#pragma unroll
      for (int c = 0; c < 4; ++c) {
        float v = acc[r][c][q] + bv[c] + yy * z0[c] + dd * z1[c];
        dst[(size_t)gm * ldc + colb + wn * 64 + c * 16 + l15] = __float2bfloat16(eluf(v));
      }
    }
  }
}

// fused layer-2 + t-layer-2: blocks [0,3072) = y1|d1|z1 (K=1024, XCD-swizzled),
// blocks [3072,3328) = t1 (K=256). hz rows written permuted via rank[].
__global__ __launch_bounds__(256) void gemm_l2t_k(
    const bf16* __restrict__ a1y, const bf16* __restrict__ a1d,
    const bf16* __restrict__ a1z, const bf16* __restrict__ ht1,
    const bf16* __restrict__ BtL2, const bf16* __restrict__ tw1t,
    const float* __restrict__ biasL2, const float* __restrict__ tb1,
    bf16* __restrict__ hyd, bf16* __restrict__ hzg, bf16* __restrict__ ht2,
    const int* __restrict__ rank) {
  __shared__ bf16 As[128 * 64];
  __shared__ bf16 Bs[128 * 64];
  const int tid = threadIdx.x, lane = tid & 63, wid = tid >> 6;
  const int wm = wid >> 1, wn = wid & 1, quad = lane >> 4, l15 = lane & 15;
  const int id = blockIdx.x;
  int bm0, bn0, Ka, g;
  const bf16 *Aptr, *Bptr;
  if (id < 3072) {
    const int xcd = id & 7, lid = id >> 3;               // lid in [0,384)
    const int pass = lid / 192, rem = lid - pass * 192;  // 192 = 8m x 24n
    const int mt = xcd * 16 + pass * 8 + (rem & 7), nt = rem >> 3;
    bm0 = mt * 128; bn0 = nt * 128; Ka = 1024;
    g = nt >> 3;
    Aptr = (g == 0) ? a1y : (g == 1) ? a1d : a1z;
    Bptr = BtL2;
  } else {
    const int local = id - 3072;
    bm0 = (local >> 1) * 128; bn0 = (local & 1) * 128; Ka = 256;
    g = 3; Aptr = ht1; Bptr = tw1t;
  }
  const int sr3 = tid >> 3, scol = ((tid & 7) ^ (sr3 & 7)) * 8;
  const bf16* gA[4];
  const bf16* gB[4];
#pragma unroll
  for (int c = 0; c < 4; ++c) {
    gA[c] = Aptr + (size_t)(bm0 + c * 32 + sr3) * Ka + scol;
    gB[c] = Bptr + (size_t)(bn0 + c * 32 + sr3) * Ka + scol;
  }
  const bf16* aBase = &As[(wm * 64 + l15) * 64];
  const bf16* bBase = &Bs[(wn * 64 + l15) * 64];
  int colsel[2];
#pragma unroll
  for (int s = 0; s < 2; ++s) colsel[s] = ((s * 4 + quad) ^ (l15 & 7)) * 8;
  f32x4 acc[4][4] = {};
  kloop64<4, 4>(gA, gB, As, Bs, tid, aBase, bBase, colsel, acc, Ka >> 6);

  const float* bias = (g == 3) ? tb1 : biasL2;
  float bv[4];
#pragma unroll
  for (int c = 0; c < 4; ++c) bv[c] = bias[bn0 + wn * 64 + c * 16 + l15];
#pragma unroll
  for (int r = 0; r < 4; ++r) {
#pragma unroll
    for (int q = 0; q < 4; ++q) {
      int gm = bm0 + wm * 64 + r * 16 + quad * 4 + q;
      bf16* dst; size_t rowoff;
      if (g == 2) { dst = hzg; rowoff = (size_t)rank[gm] * 1024 + (size_t)(bn0 - 2048); }
      else if (g == 3) { dst = ht2; rowoff = (size_t)gm * 256 + bn0; }
      else { dst = hyd; rowoff = (size_t)gm * 2048 + bn0; }
#pragma unroll
      for (int c = 0; c < 4; ++c) {
        float v = acc[r][c][q] + bv[c];
        dst[rowoff + wn * 64 + c * 16 + l15] = __float2bfloat16(eluf(v));
      }
    }
  }
}

// ---------------------------------------------------------------------------
// merged tail: z-head bucketed GEMM (blocks < ZB) + y/d heads + t-logits.
// zhead: per-bucket [cnt x 1024] x [1024 x 512], 128x64 tiles, BK=64 swizzle.
#define ZMT 28  // max m-tiles per bucket (covers 3584 rows; mean 2341, +27 sigma)
#define ZB (7 * ZMT * 8)
__global__ __launch_bounds__(256) void tail_k(
    const bf16* __restrict__ hzg, const bf16* __restrict__ zhWt,
    const float* __restrict__ zhb, const int* __restrict__ seg,
    const int* __restrict__ cnts, const int* __restrict__ sids,
    const bf16* __restrict__ hyd, const bf16* __restrict__ ht2,
    const int* __restrict__ t, const float* __restrict__ yhW,
    const float* __restrict__ yhb, const float* __restrict__ dhW,
    const float* __restrict__ dhb, const float* __restrict__ tw2,
    const float* __restrict__ tb2, float* __restrict__ out) {
  __shared__ bf16 As[128 * 64];  // 16 KB
  __shared__ bf16 Bs[64 * 64];   // 8 KB
  const int tid = threadIdx.x, lane = tid & 63, wid = tid >> 6;
  const int wv = wid, quad = lane >> 4, l15 = lane & 15;
  if (blockIdx.x < ZB) {
    const int kb = blockIdx.x / (ZMT * 8);
    const int r = blockIdx.x % (ZMT * 8);
    const int cnt = cnts[kb];
    const int bm0 = (r >> 3) * 128;
    if (bm0 >= cnt) return;
    const int n0 = (r & 7) * 64;
    const int wm = wid >> 1, wn = wid & 1;
    const int base = seg[kb];
    const int sr3 = tid >> 3, scol = ((tid & 7) ^ (sr3 & 7)) * 8;
    const bf16* gA[4];
    const bf16* gB[2];
#pragma unroll
    for (int c = 0; c < 4; ++c) {
      int rr = bm0 + c * 32 + sr3;
      if (rr >= cnt) rr = cnt - 1;
      gA[c] = hzg + (size_t)(base + rr) * 1024 + scol;
    }
#pragma unroll
    for (int c = 0; c < 2; ++c)
      gB[c] = zhWt + (size_t)kb * 512 * 1024 + (size_t)(n0 + c * 32 + sr3) * 1024 + scol;
    const bf16* aBase = &As[(wm * 64 + l15) * 64];
    const bf16* bBase = &Bs[(wn * 32 + l15) * 64];
    int colsel[2];
#pragma unroll
    for (int s = 0; s < 2; ++s) colsel[s] = ((s * 4 + quad) ^ (l15 & 7)) * 8;
    f32x4 acc[4][2] = {};
    kloop64<2, 2>(gA, gB, As, Bs, tid, aBase, bBase, colsel, acc, 16);
    const float* bias = zhb + (size_t)kb * 512;
    float bv[2]; int gnn[2];
#pragma unroll
    for (int c = 0; c < 2; ++c) {
      gnn[c] = n0 + wn * 32 + c * 16 + l15;
      bv[c] = bias[gnn[c]];
    }
#pragma unroll
    for (int r2 = 0; r2 < 4; ++r2)
#pragma unroll
      for (int q = 0; q < 4; ++q) {
        int lm = bm0 + wm * 64 + r2 * 16 + quad * 4 + q;
        if (lm < cnt) {
          int gm = sids[base + lm];
          size_t ob = (size_t)gm * 523 + 11;
#pragma unroll
          for (int c = 0; c < 2; ++c) {
            float v = acc[r2][c][q] + bv[c];
            int n = gnn[c];
            out[ob + n] = (n < 256) ? fminf(fmaxf(v, -100.f), 100.f)
                                    : fminf(softplusf(v) + 0.001f, 100.f);
          }
        }
      }
    return;
  }
  const int hid = blockIdx.x - ZB;
  if (hid < 4096) {  // y/d heads
    const int b = hid * 4 + wv;
    const int tb = t[b];
    const float* yW = yhW + (size_t)tb * 2048;
    const float* dW = dhW + (size_t)tb * 2048;
    float s0 = 0.f, s1 = 0.f, s2 = 0.f, s3 = 0.f;
    for (int i = lane; i < 1024; i += 64) {
      float a = __bfloat162float(hyd[(size_t)b * 2048 + i]);
      float c = __bfloat162float(hyd[(size_t)b * 2048 + 1024 + i]);
      s0 += a * yW[2 * i]; s1 += a * yW[2 * i + 1];
      s2 += c * dW[2 * i]; s3 += c * dW[2 * i + 1];
    }
#pragma unroll
    for (int off = 32; off > 0; off >>= 1) {
      s0 += __shfl_down(s0, off); s1 += __shfl_down(s1, off);
      s2 += __shfl_down(s2, off); s3 += __shfl_down(s3, off);
    }
    if (lane == 0) {
      size_t o = (size_t)b * 523;
      out[o + 7] = fminf(fmaxf(s0 + yhb[tb * 2], -1e6f), 1e6f);
      out[o + 8] = fminf(softplusf(s1 + yhb[tb * 2 + 1]) + 1e-3f, 1e6f);
      out[o + 9] = fminf(fmaxf(s2 + dhb[tb * 2], -1e6f), 1e6f);
      out[o + 10] = fminf(softplusf(s3 + dhb[tb * 2 + 1]) + 1e-3f, 1e6f);
    }
  } else {  // t logits
    const int b = (hid - 4096) * 4 + wv;
    float h[4];
#pragma unroll
    for (int j = 0; j < 4; ++j)
      h[j] = __bfloat162float(ht2[(size_t)b * 256 + lane * 4 + j]);
    float pp[7];
#pragma unroll
    for (int kk = 0; kk < 7; ++kk) {
      float s = 0.f;
#pragma unroll
      for (int j = 0; j < 4; ++j) s += h[j] * tw2[(lane * 4 + j) * 7 + kk];
      pp[kk] = s;
    }
#pragma unroll
    for (int kk = 0; kk < 7; ++kk)
#pragma unroll
      for (int off = 32; off > 0; off >>= 1) pp[kk] += __shfl_down(pp[kk], off);
    if (lane == 0) {
#pragma unroll
      for (int kk = 0; kk < 7; ++kk) {
        float v = eluf(pp[kk] + tb2[kk]);
        out[(size_t)b * 523 + kk] = fminf(fmaxf(v, -10.f), 10.f);
      }
    }
  }
}

// ---------------------------------------------------------------------------
extern "C" void kernel_launch(void* const* d_in, const int* in_sizes, int n_in,
                              void* d_out, int out_size, void* d_ws, size_t ws_size,
                              hipStream_t stream) {
  const float* x   = (const float*)d_in[0];
  const int*   t   = (const int*)d_in[1];
  const float* yv  = (const float*)d_in[2];
  const float* dv  = (const float*)d_in[3];
  const float* tw0 = (const float*)d_in[4];
  const float* tb0 = (const float*)d_in[5];
  const float* tw1 = (const float*)d_in[6];
  const float* tb1 = (const float*)d_in[7];
  const float* tw2 = (const float*)d_in[8];
  const float* tb2 = (const float*)d_in[9];
  const float* yw0 = (const float*)d_in[10];
  const float* yb0 = (const float*)d_in[11];
  const float* yw1 = (const float*)d_in[12];
  const float* yb1 = (const float*)d_in[13];
  const float* yhW = (const float*)d_in[14];
  const float* yhb = (const float*)d_in[15];
  const float* dw0 = (const float*)d_in[16];
  const float* db0 = (const float*)d_in[17];
  const float* dw1 = (const float*)d_in[18];
  const float* db1 = (const float*)d_in[19];
  const float* dhW = (const float*)d_in[20];
  const float* dhb = (const float*)d_in[21];
  const float* zw0 = (const float*)d_in[22];
  const float* zb0 = (const float*)d_in[23];
  const float* zw1 = (const float*)d_in[24];
  const float* zb1 = (const float*)d_in[25];
  const float* zhW = (const float*)d_in[26];
  const float* zhb = (const float*)d_in[27];
  float* out = (float*)d_out;

  const int B = 16384;
  char* p = (char*)d_ws;
  auto take = [&](size_t bytes) {
    char* r = p;
    p += (bytes + 255) & ~(size_t)255;
    return r;
  };
  bf16*  BtL1    = (bf16*)take((size_t)3328 * 1024 * 2);
  bf16*  BtL2    = (bf16*)take((size_t)3072 * 1024 * 2);
  bf16*  tw1t    = (bf16*)take((size_t)256 * 256 * 2);
  bf16*  zhWt    = (bf16*)take((size_t)7 * 512 * 1024 * 2);
  float* biasAll = (float*)take(3328 * 4);
  float* r0All   = (float*)take(3328 * 4);
  float* r1All   = (float*)take(3328 * 4);
  float* biasL2  = (float*)take(3072 * 4);
  int*   cnt     = (int*)take(8 * 4);
  int*   seg     = (int*)take(8 * 4);
  int*   rank    = (int*)take((size_t)B * 4);
  int*   sids    = (int*)take((size_t)B * 4);
  bf16*  xb      = (bf16*)take((size_t)B * 1024 * 2);  // reused as hzg after L1
  bf16*  a1y     = (bf16*)take((size_t)B * 1024 * 2);
  bf16*  a1d     = (bf16*)take((size_t)B * 1024 * 2);
  bf16*  a1z     = (bf16*)take((size_t)B * 1024 * 2);
  bf16*  ht1     = (bf16*)take((size_t)B * 256 * 2);
  bf16*  hyd     = (bf16*)take((size_t)B * 2048 * 2);
  bf16*  ht2     = (bf16*)take((size_t)B * 256 * 2);
  bf16*  hzg     = xb;

  book_k<<<1, 1024, 0, stream>>>(t, cnt, seg, rank, sids);
  prep_all_k<<<19021, 256, 0, stream>>>(x, xb, yw0, dw0, zw0, tw0, BtL1,
                                        yw1, dw1, zw1, BtL2, tw1, tw1t, zhW, zhWt,
                                        yb0, db0, zb0, tb0, yb1, db1, zb1,
                                        biasAll, r0All, r1All, biasL2);
  gemm_l1_k<<<3328, 256, 0, stream>>>(xb, BtL1, biasAll, r0All, r1All,
                                      yv, dv, a1y, a1d, a1z, ht1);
  gemm_l2t_k<<<3328, 256, 0, stream>>>(a1y, a1d, a1z, ht1, BtL2, tw1t,
                                       biasL2, tb1, hyd, hzg, ht2, rank);
  tail_k<<<ZB + 8192, 256, 0, stream>>>(hzg, zhWt, zhb, seg, cnt, sids,
                                        hyd, ht2, t, yhW, yhb, dhW, dhb,
                                        tw2, tb2, out);
}